// Round 18
// baseline (781.856 us; speedup 1.0000x reference)
//
#include <hip/hip_runtime.h>
#include <hip/hip_bf16.h>
#include <math.h>

#define NNODES 65536
#define NEDGES 1048576
#define NGRAPHS 64

typedef __attribute__((ext_vector_type(8))) short short8;
typedef __attribute__((ext_vector_type(4))) float f32x4;
typedef __attribute__((ext_vector_type(16))) float f32x16;

// ---- order-preserving float<->uint encoding for atomicMax-based max ----
__device__ __forceinline__ unsigned encf(float f) {
    unsigned u = __float_as_uint(f);
    return (u & 0x80000000u) ? ~u : (u | 0x80000000u);
}
__device__ __forceinline__ float decf(unsigned u) {
    unsigned v = (u & 0x80000000u) ? (u & 0x7FFFFFFFu) : ~u;
    return __uint_as_float(v);
}
#define ENC_NEG_INF 0x007FFFFFu   // encf(-inf)

// RNE float -> bf16 bits (finite values only)
__device__ __forceinline__ unsigned bfbits(float f) {
    unsigned u = __float_as_uint(f);
    return (u + 0x7FFFu + ((u >> 16) & 1u)) >> 16;
}
__device__ __forceinline__ float bfval(unsigned bits) { return __uint_as_float(bits << 16); }
// HOT path: HW packed RNE convert (1 VALU op / 2 elems). Round-8 lesson:
// __float2bfloat16 is NOT RNE on this toolchain; v_cvt_pk_bf16_f32 is RNE
// in HW and matches bfbits (verified passing rounds 10-17).
__device__ __forceinline__ unsigned pk2(float a, float b) {
    unsigned r;
    asm("v_cvt_pk_bf16_f32 %0, %1, %2" : "=v"(r) : "v"(a), "v"(b));
    return r;   // a -> low 16, b -> high 16
}
__device__ __forceinline__ float bflo(unsigned p) { return __uint_as_float(p << 16); }
__device__ __forceinline__ float bfhi(unsigned p) { return __uint_as_float(p & 0xFFFF0000u); }

// ============================ CSR build ============================
__global__ void k_init(int* deg, int* cursor, unsigned* poolEnc) {
    int i = blockIdx.x * 256 + threadIdx.x;
    if (i < NNODES) { deg[i] = 0; cursor[i] = 0; }
    if (i < NGRAPHS * 256) poolEnc[i] = ENC_NEG_INF;
}

__global__ void k_count(const int* __restrict__ ei, int* deg) {
    int e = blockIdx.x * 256 + threadIdx.x;
    atomicAdd(&deg[ei[NEDGES + e]], 1);
}

__global__ void k_scan1(const int* __restrict__ deg, int* rowptr, int* bsum) {
    __shared__ int s[256];
    int t = threadIdx.x, b = blockIdx.x;
    int v = deg[b * 256 + t];
    s[t] = v;
    __syncthreads();
    for (int off = 1; off < 256; off <<= 1) {
        int x = (t >= off) ? s[t - off] : 0;
        __syncthreads();
        if (t >= off) s[t] += x;
        __syncthreads();
    }
    rowptr[b * 256 + t] = s[t] - v;       // local exclusive
    if (t == 255) bsum[b] = s[255];
}

__global__ void k_scan2(const int* __restrict__ bsum, int* boff) {
    __shared__ int s[256];
    int t = threadIdx.x;
    int v = bsum[t];
    s[t] = v;
    __syncthreads();
    for (int off = 1; off < 256; off <<= 1) {
        int x = (t >= off) ? s[t - off] : 0;
        __syncthreads();
        if (t >= off) s[t] += x;
        __syncthreads();
    }
    boff[t] = s[t] - v;                   // exclusive block offsets
}

__global__ void k_scan3(int* rowptr, const int* __restrict__ boff) {
    int i = blockIdx.x * 256 + threadIdx.x;
    rowptr[i] += boff[blockIdx.x];
    if (i == 0) rowptr[NNODES] = NEDGES;
}

__global__ void k_scatter(const int* __restrict__ ei, const int* __restrict__ rowptr,
                          int* cursor, int* csr_src, int* csr_dst) {
    int e = blockIdx.x * 256 + threadIdx.x;
    int s = ei[e], d = ei[NEDGES + e];
    int pos = rowptr[d] + atomicAdd(&cursor[d], 1);
    csr_src[pos] = s;
    csr_dst[pos] = d;
}

// ============ W2 -> bf16 fragment-ordered prep (for k_agg32's B loads) ============
// W2b[((cw*KS16+ks)*64 + lane)*8 + j] = bf16(W2[k][col]),
// k = ks*16 + (lane>>5)*8 + j, col = cw*32 + (lane&31).
// One coalesced 16B/lane global load per (wave,ks) inside k_agg32 — W2 stays
// L2-resident (128 KB) so the B-operand costs ZERO registers.
template <int H, int F>
__global__ __launch_bounds__(256) void k_w2prep(const float* __restrict__ W2,
                                                unsigned short* __restrict__ W2b) {
    constexpr int KS16 = H / 16;
    int o = blockIdx.x * 256 + threadIdx.x;       // over H*F outputs
    int j = o & 7;
    int lane = (o >> 3) & 63;
    int t = o >> 9;
    int ks = t % KS16;
    int cw = t / KS16;
    int k = ks * 16 + (lane >> 5) * 8 + j;
    int col = cw * 32 + (lane & 31);
    W2b[o] = (unsigned short)bfbits(W2[(size_t)k * F + col]);
}

// ============================ U/V precompute ============================
// Scalar VALU version — kept for layer 1 only (FIN=3: no MFMA fit).
template <int FIN, int H>
__global__ __launch_bounds__(256) void k_uv(const float* __restrict__ X,
                                            const float* __restrict__ W1,
                                            const float* __restrict__ B1,
                                            float* __restrict__ U,
                                            unsigned short* __restrict__ Vb) {
    constexpr int NPT = (16 * H) / 256;   // nodes per thread
    __shared__ float xs[16][FIN];
    int tid = threadIdx.x;
    int n0 = blockIdx.x * 16;
    for (int idx = tid; idx < 16 * FIN; idx += 256)
        xs[idx / FIN][idx % FIN] = X[(size_t)(n0 + idx / FIN) * FIN + (idx % FIN)];
    __syncthreads();
    int h = tid & (H - 1);
    int nb = (tid / H) * NPT;
    float u[NPT], v[NPT];
    float bb = B1[h];
#pragma unroll
    for (int n = 0; n < NPT; n++) { u[n] = bb; v[n] = 0.f; }
    for (int f = 0; f < FIN; f++) {
        float wt = W1[f * H + h];
        float wb = W1[(FIN + f) * H + h];
        float wd = wt - wb;
#pragma unroll
        for (int n = 0; n < NPT; n++) {
            float xv = xs[nb + n][f];
            u[n] += xv * wd;
            v[n] += xv * wb;
        }
    }
#pragma unroll
    for (int n = 0; n < NPT; n++) {
        U[(size_t)(n0 + nb + n) * H + h] = u[n];
        Vb[(size_t)(n0 + nb + n) * H + h] = (unsigned short)bfbits(v[n]);
    }
}

// ==================== U/V precompute via MFMA (layers 2,3) ====================
// Split precision (verified round 12): S = Xhi@Whi + Xhi@Wlo + Xlo@Whi.
template <int FIN, int H>
__global__ __launch_bounds__((H / 16) * 64)
void k_uv_mfma(const float* __restrict__ X,
               const float* __restrict__ W1,
               const float* __restrict__ B1,
               float* __restrict__ U,
               unsigned short* __restrict__ Vb) {
    constexpr int WAVES = H / 16;
    constexpr int BLOCK = WAVES * 64;
    constexpr int KS = FIN / 32;          // k-steps
    constexpr int NPB = 16;               // node-tiles (of 16) per block
    constexpr int FP = FIN + 8;           // padded LDS row (bf16 units)
    static_assert(FIN % 32 == 0 && (16 * FIN) % (2 * BLOCK) == 0, "shape");

    __shared__ unsigned short xhi[16 * FP];
    __shared__ unsigned short xlo[16 * FP];

    int tid = threadIdx.x;
    int ln = tid & 15;
    int qd = (tid >> 4) & 3;
    int wv = tid >> 6;
    int col = wv * 16 + ln;

    short8 bth[KS], btl[KS], bbh[KS], bbl[KS];
#pragma unroll
    for (int ks = 0; ks < KS; ks++) {
        int kb = ks * 32 + qd * 8;
        short8 th, tl, bh, bl;
#pragma unroll
        for (int j = 0; j < 8; j++) {
            float wt = W1[(size_t)(kb + j) * H + col];
            float wb = W1[(size_t)(FIN + kb + j) * H + col];
            unsigned thb = bfbits(wt), bhb = bfbits(wb);
            th[j] = (short)thb;
            bh[j] = (short)bhb;
            tl[j] = (short)bfbits(wt - bfval(thb));
            bl[j] = (short)bfbits(wb - bfval(bhb));
        }
        bth[ks] = th; btl[ks] = tl; bbh[ks] = bh; bbl[ks] = bl;
    }

    float bias = B1[col];
    int nbase0 = blockIdx.x * (NPB * 16);

    int sidx = tid * 2;
    int snode = sidx / FIN;               // 0..15
    int sf = sidx % FIN;

    float2 xr = *(const float2*)&X[(size_t)(nbase0 + snode) * FIN + sf];

    for (int t = 0; t < NPB; t++) {
        unsigned h0 = bfbits(xr.x), h1 = bfbits(xr.y);
        unsigned l0 = bfbits(xr.x - bfval(h0));
        unsigned l1 = bfbits(xr.y - bfval(h1));
        *(unsigned*)&xhi[snode * FP + sf] = h0 | (h1 << 16);
        *(unsigned*)&xlo[snode * FP + sf] = l0 | (l1 << 16);
        if (t + 1 < NPB)
            xr = *(const float2*)&X[(size_t)(nbase0 + (t + 1) * 16 + snode) * FIN + sf];
        __syncthreads();

        f32x4 at = (f32x4){0.f, 0.f, 0.f, 0.f};
        f32x4 ab = (f32x4){0.f, 0.f, 0.f, 0.f};
#pragma unroll
        for (int ks = 0; ks < KS; ks++) {
            int ko = ks * 32 + qd * 8;
            short8 ah = *(const short8*)&xhi[ln * FP + ko];
            short8 al = *(const short8*)&xlo[ln * FP + ko];
            at = __builtin_amdgcn_mfma_f32_16x16x32_bf16(ah, bth[ks], at, 0, 0, 0);
            at = __builtin_amdgcn_mfma_f32_16x16x32_bf16(ah, btl[ks], at, 0, 0, 0);
            at = __builtin_amdgcn_mfma_f32_16x16x32_bf16(al, bth[ks], at, 0, 0, 0);
            ab = __builtin_amdgcn_mfma_f32_16x16x32_bf16(ah, bbh[ks], ab, 0, 0, 0);
            ab = __builtin_amdgcn_mfma_f32_16x16x32_bf16(ah, bbl[ks], ab, 0, 0, 0);
            ab = __builtin_amdgcn_mfma_f32_16x16x32_bf16(al, bbh[ks], ab, 0, 0, 0);
        }

        int nb = nbase0 + t * 16 + qd * 4;
#pragma unroll
        for (int j = 0; j < 4; j++) {
            U[(size_t)(nb + j) * H + col] = at[j] - ab[j] + bias;   // X@(Wt-Wb)+b
            Vb[(size_t)(nb + j) * H + col] = (unsigned short)bfbits(ab[j]); // X@Wb
        }
        __syncthreads();   // tile consumed before next overwrite
    }
}

// ================= fused edge-GEMM (MFMA bf16 16x16) + segment-max =================
// Verified round-13 version — layer 1. Round-5 pipeline + pk2 asm + NPG.
template <int H, int F, int RWAVES, int CWAVES, int NPG>
__global__ __launch_bounds__(RWAVES * CWAVES * 64)
void k_agg(const float* __restrict__ U,
           const unsigned short* __restrict__ Vb,
           const float* __restrict__ W2,
           const float* __restrict__ B2,
           const int* __restrict__ rowptr,
           const int* __restrict__ csr_src,
           const int* __restrict__ csr_dst,
           float* __restrict__ Y) {
    constexpr int BLOCK = RWAVES * CWAVES * 64;
    constexpr int TR = 32 * RWAVES;         // edge rows per tile
    constexpr int HP = H + 8;               // padded row (bf16 units), 16B-aligned frags
    constexpr int CPW = F / CWAVES;         // cols per wave
    constexpr int NT = CPW / 16;            // n-tiles per wave
    constexpr int KS = H / 32;              // k-steps
    constexpr int ACCSTR = F + 1;           // bank-spread accumulator stride
    constexpr int LPR = H / 8;              // threads per hidden row (8 elems each)
    constexpr int RPP = BLOCK / LPR;        // rows per construction pass
    constexpr int NPASS = TR / RPP;         // construction passes per tile
    static_assert(H % 32 == 0 && NT >= 1 && RPP >= 1 && TR % RPP == 0, "shape");
    static_assert(NPG <= 120, "slot fits signed char");

    __shared__ unsigned short hs[2][TR * HP];   // double-buffered hidden tile
    __shared__ unsigned accs[NPG * ACCSTR];     // per-slot running max (encoded)
    __shared__ int srcA[2][TR];
    __shared__ __align__(4) signed char slotB[2][TR];

    int tid = threadIdx.x;
    int n0 = blockIdx.x * NPG;

    int ln = tid & 15;              // MFMA n/m lane index
    int qd = (tid >> 4) & 3;        // MFMA quad
    int wv = tid >> 6;
    int rw = wv / CWAVES;           // row group
    int cw = wv % CWAVES;           // col wave

    short8 Bf[NT][KS];
#pragma unroll
    for (int nt = 0; nt < NT; nt++) {
        int col = cw * CPW + nt * 16 + ln;
#pragma unroll
        for (int ks = 0; ks < KS; ks++) {
            int kb = ks * 32 + qd * 8;
            short8 b;
#pragma unroll
            for (int j = 0; j < 8; j++)
                b[j] = (short)bfbits(W2[(size_t)(kb + j) * F + col]);
            Bf[nt][ks] = b;
        }
    }

    for (int idx = tid; idx < NPG * ACCSTR; idx += BLOCK) accs[idx] = ENC_NEG_INF;

    int e0 = rowptr[n0], e1 = rowptr[n0 + NPG];
    int ntile = (e1 - e0 + TR - 1) / TR;

    int rid = tid / LPR;            // construction: my row within a pass
    int kk = (tid % LPR) * 8;       // construction: my 8-elem chunk

    if (tid < TR) {
        int p = e0 + tid;
        int s = 0; signed char sl = -1;
        if (p < e1) { s = csr_src[p]; sl = (signed char)(csr_dst[p] - n0); }
        srcA[0][tid] = s; slotB[0][tid] = sl;
    }
    __syncthreads();

    auto mfma_tile = [&](int buf, char4 s0, char4 s1) {
        f32x4 acc[2][NT];
#pragma unroll
        for (int mt = 0; mt < 2; mt++)
#pragma unroll
            for (int nt = 0; nt < NT; nt++)
                acc[mt][nt] = (f32x4){0.f, 0.f, 0.f, 0.f};

#pragma unroll
        for (int ks = 0; ks < KS; ks++) {
            int ko = ks * 32 + qd * 8;
            short8 a0 = *(const short8*)&hs[buf][(rw * 32 + ln) * HP + ko];
            short8 a1 = *(const short8*)&hs[buf][(rw * 32 + 16 + ln) * HP + ko];
#pragma unroll
            for (int nt = 0; nt < NT; nt++) {
                acc[0][nt] = __builtin_amdgcn_mfma_f32_16x16x32_bf16(a0, Bf[nt][ks], acc[0][nt], 0, 0, 0);
                acc[1][nt] = __builtin_amdgcn_mfma_f32_16x16x32_bf16(a1, Bf[nt][ks], acc[1][nt], 0, 0, 0);
            }
        }

#pragma unroll
        for (int mt = 0; mt < 2; mt++) {
            char4 ss = mt ? s1 : s0;
#pragma unroll
            for (int nt = 0; nt < NT; nt++) {
                int colw = cw * CPW + nt * 16 + ln;
                float c0 = acc[mt][nt][0], c1 = acc[mt][nt][1];
                float c2 = acc[mt][nt][2], c3 = acc[mt][nt][3];
                float m3 = c3;
                float m2 = (ss.z == ss.w) ? fmaxf(c2, m3) : c2;
                float m1 = (ss.y == ss.z) ? fmaxf(c1, m2) : c1;
                float m0 = (ss.x == ss.y) ? fmaxf(c0, m1) : c0;
                if (ss.x >= 0)                 atomicMax(&accs[(int)ss.x * ACCSTR + colw], encf(m0));
                if (ss.y >= 0 && ss.y != ss.x) atomicMax(&accs[(int)ss.y * ACCSTR + colw], encf(m1));
                if (ss.z >= 0 && ss.z != ss.y) atomicMax(&accs[(int)ss.z * ACCSTR + colw], encf(m2));
                if (ss.w >= 0 && ss.w != ss.z) atomicMax(&accs[(int)ss.w * ACCSTR + colw], encf(m3));
            }
        }
    };

    char4 ssp0 = make_char4(-1, -1, -1, -1), ssp1 = make_char4(-1, -1, -1, -1);
    int prevbuf = 0;

    for (int t = 0; t < ntile; t++) {
        int cur = t & 1;

        int msrc[NPASS]; int msl[NPASS];
#pragma unroll
        for (int ps = 0; ps < NPASS; ps++) {
            int r = ps * RPP + rid;
            msrc[ps] = srcA[cur][r];
            msl[ps] = slotB[cur][r];
        }
        uint4 vreg[NPASS];
#pragma unroll
        for (int ps = 0; ps < NPASS; ps++)
            vreg[ps] = *(const uint4*)&Vb[(size_t)msrc[ps] * H + kk];   // src=0 for pad rows: safe
        char4 ssc0 = *(const char4*)&slotB[cur][rw * 32 + qd * 4];
        char4 ssc1 = *(const char4*)&slotB[cur][rw * 32 + 16 + qd * 4];

        int nsrc = 0; signed char nsl = -1;
        bool hn = (t + 1 < ntile);
        if (hn && tid < TR) {
            int p = e0 + (t + 1) * TR + tid;
            if (p < e1) { nsrc = csr_src[p]; nsl = (signed char)(csr_dst[p] - n0); }
        }

        if (t > 0) mfma_tile(prevbuf, ssp0, ssp1);

#pragma unroll
        for (int ps = 0; ps < NPASS; ps++) {
            int r = ps * RPP + rid;
            uint4 w;
            if (msl[ps] >= 0) {
                const float4 ua = *(const float4*)&U[(size_t)(n0 + msl[ps]) * H + kk];
                const float4 ub = *(const float4*)&U[(size_t)(n0 + msl[ps]) * H + kk + 4];
                const uint4 vv = vreg[ps];
                w.x = pk2(fmaxf(ua.x + bflo(vv.x), 0.f), fmaxf(ua.y + bfhi(vv.x), 0.f));
                w.y = pk2(fmaxf(ua.z + bflo(vv.y), 0.f), fmaxf(ua.w + bfhi(vv.y), 0.f));
                w.z = pk2(fmaxf(ub.x + bflo(vv.z), 0.f), fmaxf(ub.y + bfhi(vv.z), 0.f));
                w.w = pk2(fmaxf(ub.z + bflo(vv.w), 0.f), fmaxf(ub.w + bfhi(vv.w), 0.f));
            } else {
                w = (uint4){0u, 0u, 0u, 0u};
            }
            *(uint4*)&hs[cur][r * HP + kk] = w;
        }

        if (hn && tid < TR) { srcA[cur ^ 1][tid] = nsrc; slotB[cur ^ 1][tid] = nsl; }

        __syncthreads();
        ssp0 = ssc0; ssp1 = ssc1; prevbuf = cur;
    }
    if (ntile > 0) mfma_tile(prevbuf, ssp0, ssp1);
    __syncthreads();

    for (int idx = tid; idx < NPG * F; idx += BLOCK) {
        int sl = idx / F, cc = idx % F;
        float m = decf(accs[sl * ACCSTR + cc]);
        float o = isfinite(m) ? (m + B2[cc]) : 0.f;   // empty segment -> 0
        Y[(size_t)(n0 + sl) * F + cc] = o;
    }
}

// ============ fused edge-GEMM (MFMA bf16 32x32) + segment-max — layers 2,3 ============
// 32x32x16 MFMA (conflicts=0, A-redundancy F/32), B streamed from L2
// (fragment-ordered W2b, zero B-registers — round-17 verified, spill gone).
// Round-18: RWAVES=1 (TR=32) shrinks LDS so MULTIPLE blocks co-reside per CU
// (L3: 65.4 KB -> 2 blocks; L2: 34 KB -> 4 blocks). Independent barrier
// domains overlap one block's construction/gather with another's MFMA —
// round-7 reinterpretation: its 2-block residency absorbed ~2x duplicated
// work at only +4% time, so overlap works; this applies it WITHOUT waste.
template <int H, int F, int RWAVES, int NPG>
__global__ __launch_bounds__(RWAVES * (F / 32) * 64)
void k_agg32(const float* __restrict__ U,
             const unsigned short* __restrict__ Vb,
             const unsigned short* __restrict__ W2b,
             const float* __restrict__ B2,
             const int* __restrict__ rowptr,
             const int* __restrict__ csr_src,
             const int* __restrict__ csr_dst,
             float* __restrict__ Y) {
    constexpr int CWAVES = F / 32;
    constexpr int BLOCK = RWAVES * CWAVES * 64;
    constexpr int TR = 32 * RWAVES;         // edge rows per tile
    constexpr int HP = H + 8;               // padded row (bf16), 16B-aligned
    constexpr int KS16 = H / 16;            // k-steps of 16
    constexpr int ACCSTR = F + 1;
    constexpr int LPR = H / 8;
    constexpr int RPP = BLOCK / LPR;
    constexpr int NPASS = TR / RPP;
    static_assert(H % 16 == 0 && TR % RPP == 0 && NPG <= 120, "shape");

    __shared__ unsigned short hs[2][TR * HP];
    __shared__ unsigned accs[NPG * ACCSTR];
    __shared__ int srcA[2][TR];
    __shared__ __align__(4) signed char slotB[2][TR];

    int tid = threadIdx.x;
    int n0 = blockIdx.x * NPG;

    int ln32 = tid & 31;            // MFMA row/col lane
    int kh = (tid >> 5) & 1;        // k-octet selector
    int wv = tid >> 6;
    int rw = wv / CWAVES;           // row group
    int cw = wv % CWAVES;           // col wave

    // per-lane base into fragment-ordered W2b: frag(cw,ks) at ((cw*KS16+ks)*64+lane)*8
    const unsigned short* Bp = W2b + ((size_t)(cw * KS16) * 64 + (tid & 63)) * 8;

    for (int idx = tid; idx < NPG * ACCSTR; idx += BLOCK) accs[idx] = ENC_NEG_INF;

    int e0 = rowptr[n0], e1 = rowptr[n0 + NPG];
    int ntile = (e1 - e0 + TR - 1) / TR;

    int rid = tid / LPR;
    int kk = (tid % LPR) * 8;

    if (tid < TR) {
        int p = e0 + tid;
        int s = 0; signed char sl = -1;
        if (p < e1) { s = csr_src[p]; sl = (signed char)(csr_dst[p] - n0); }
        srcA[0][tid] = s; slotB[0][tid] = sl;
    }
    __syncthreads();

    // MFMA + segmented max for one completed tile (B-frags streamed from L2)
    auto mfma_tile = [&](int buf, char4 sA, char4 sB, char4 sC, char4 sD) {
        f32x16 acc;
#pragma unroll
        for (int j = 0; j < 16; j++) acc[j] = 0.f;

#pragma unroll
        for (int ks = 0; ks < KS16; ks++) {
            short8 a = *(const short8*)&hs[buf][(rw * 32 + ln32) * HP + ks * 16 + kh * 8];
            short8 b = *(const short8*)&Bp[(size_t)ks * 64 * 8];
            acc = __builtin_amdgcn_mfma_f32_32x32x16_bf16(a, b, acc, 0, 0, 0);
        }

        int colw = cw * 32 + ln32;
#pragma unroll
        for (int rg = 0; rg < 4; rg++) {
            char4 ss = (rg == 0) ? sA : (rg == 1) ? sB : (rg == 2) ? sC : sD;
            float c0 = acc[4 * rg + 0], c1 = acc[4 * rg + 1];
            float c2 = acc[4 * rg + 2], c3 = acc[4 * rg + 3];
            float m3 = c3;
            float m2 = (ss.z == ss.w) ? fmaxf(c2, m3) : c2;
            float m1 = (ss.y == ss.z) ? fmaxf(c1, m2) : c1;
            float m0 = (ss.x == ss.y) ? fmaxf(c0, m1) : c0;
            if (ss.x >= 0)                 atomicMax(&accs[(int)ss.x * ACCSTR + colw], encf(m0));
            if (ss.y >= 0 && ss.y != ss.x) atomicMax(&accs[(int)ss.y * ACCSTR + colw], encf(m1));
            if (ss.z >= 0 && ss.z != ss.y) atomicMax(&accs[(int)ss.z * ACCSTR + colw], encf(m2));
            if (ss.w >= 0 && ss.w != ss.z) atomicMax(&accs[(int)ss.w * ACCSTR + colw], encf(m3));
        }
    };

    char4 sspA = make_char4(-1, -1, -1, -1), sspB = sspA, sspC = sspA, sspD = sspA;
    int prevbuf = 0;
    int rbase = rw * 32 + 4 * kh;   // my C-rows: rbase + 8*rg + {0..3}

    for (int t = 0; t < ntile; t++) {
        int cur = t & 1;

        // (1) tile-t metadata + EARLY V-gathers
        int msrc[NPASS]; int msl[NPASS];
#pragma unroll
        for (int ps = 0; ps < NPASS; ps++) {
            int r = ps * RPP + rid;
            msrc[ps] = srcA[cur][r];
            msl[ps] = slotB[cur][r];
        }
        uint4 vreg[NPASS];
#pragma unroll
        for (int ps = 0; ps < NPASS; ps++)
            vreg[ps] = *(const uint4*)&Vb[(size_t)msrc[ps] * H + kk];
        char4 sscA = *(const char4*)&slotB[cur][rbase + 0];
        char4 sscB = *(const char4*)&slotB[cur][rbase + 8];
        char4 sscC = *(const char4*)&slotB[cur][rbase + 16];
        char4 sscD = *(const char4*)&slotB[cur][rbase + 24];

        // (2) prefetch CSR metadata for tile t+1
        int nsrc = 0; signed char nsl = -1;
        bool hn = (t + 1 < ntile);
        if (hn && tid < TR) {
            int p = e0 + (t + 1) * TR + tid;
            if (p < e1) { nsrc = csr_src[p]; nsl = (signed char)(csr_dst[p] - n0); }
        }

        // (3) MFMA + seg-max for tile t-1
        if (t > 0) mfma_tile(prevbuf, sspA, sspB, sspC, sspD);

        // (4) build hidden tile t
#pragma unroll
        for (int ps = 0; ps < NPASS; ps++) {
            int r = ps * RPP + rid;
            uint4 w;
            if (msl[ps] >= 0) {
                const float4 ua = *(const float4*)&U[(size_t)(n0 + msl[ps]) * H + kk];
                const float4 ub = *(const float4*)&U[(size_t)(n0 + msl[ps]) * H + kk + 4];
                const uint4 vv = vreg[ps];
                w.x = pk2(fmaxf(ua.x + bflo(vv.x), 0.f), fmaxf(ua.y + bfhi(vv.x), 0.f));
                w.y = pk2(fmaxf(ua.z + bflo(vv.y), 0.f), fmaxf(ua.w + bfhi(vv.y), 0.f));
                w.z = pk2(fmaxf(ub.x + bflo(vv.z), 0.f), fmaxf(ub.y + bfhi(vv.z), 0.f));
                w.w = pk2(fmaxf(ub.z + bflo(vv.w), 0.f), fmaxf(ub.w + bfhi(vv.w), 0.f));
            } else {
                w = (uint4){0u, 0u, 0u, 0u};
            }
            *(uint4*)&hs[cur][r * HP + kk] = w;
        }

        // (5) stage next tile's CSR metadata
        if (hn && tid < TR) { srcA[cur ^ 1][tid] = nsrc; slotB[cur ^ 1][tid] = nsl; }

        // (6) one barrier per tile
        __syncthreads();
        sspA = sscA; sspB = sscB; sspC = sscC; sspD = sscD; prevbuf = cur;
    }
    if (ntile > 0) mfma_tile(prevbuf, sspA, sspB, sspC, sspD);
    __syncthreads();

    for (int idx = tid; idx < NPG * F; idx += BLOCK) {
        int sl = idx / F, cc = idx % F;
        float m = decf(accs[sl * ACCSTR + cc]);
        float o = isfinite(m) ? (m + B2[cc]) : 0.f;
        Y[(size_t)(n0 + sl) * F + cc] = o;
    }
}

// ============================ global max-pool + FC ============================
__global__ void k_pool(const float* __restrict__ X3, const int* __restrict__ batch,
                       unsigned* poolEnc) {
    int gph = blockIdx.x;
    int seg = blockIdx.y;
    int c = threadIdx.x;
    int lo = 0, hi = NNODES;
    while (lo < hi) { int mid = (lo + hi) >> 1; if (batch[mid] < gph) lo = mid + 1; else hi = mid; }
    int start = lo;
    hi = NNODES;
    while (lo < hi) { int mid = (lo + hi) >> 1; if (batch[mid] < gph + 1) lo = mid + 1; else hi = mid; }
    int end = lo;
    int chunk = (end - start + 7) >> 3;
    int s = start + seg * chunk;
    int e = min(end, s + chunk);
    float m = -INFINITY;
    for (int n = s; n < e; n++) m = fmaxf(m, X3[(size_t)n * 256 + c]);
    atomicMax(&poolEnc[gph * 256 + c], encf(m));
}

__global__ __launch_bounds__(128) void k_fc(const unsigned* __restrict__ poolEnc,
                                            const float* __restrict__ Wfc,
                                            const float* __restrict__ Bfc,
                                            float* __restrict__ out) {
    __shared__ float p[256];
    int gph = blockIdx.x, c = threadIdx.x;
    for (int k = c; k < 256; k += 128) {
        float m = decf(poolEnc[gph * 256 + k]);
        p[k] = isfinite(m) ? m : 0.f;
    }
    __syncthreads();
    float s = Bfc[c];
    for (int k = 0; k < 256; k++) s += p[k] * Wfc[k * 128 + c];
    out[gph * 128 + c] = s;
}

// ============================ launch ============================
extern "C" void kernel_launch(void* const* d_in, const int* in_sizes, int n_in,
                              void* d_out, int out_size, void* d_ws, size_t ws_size,
                              hipStream_t stream) {
    const float* x     = (const float*)d_in[0];
    const int*   ei    = (const int*)d_in[1];
    const int*   batch = (const int*)d_in[2];
    const float* w1_1 = (const float*)d_in[3];
    const float* b1_1 = (const float*)d_in[4];
    const float* w2_1 = (const float*)d_in[5];
    const float* b2_1 = (const float*)d_in[6];
    const float* w1_2 = (const float*)d_in[7];
    const float* b1_2 = (const float*)d_in[8];
    const float* w2_2 = (const float*)d_in[9];
    const float* b2_2 = (const float*)d_in[10];
    const float* w1_3 = (const float*)d_in[11];
    const float* b1_3 = (const float*)d_in[12];
    const float* w2_3 = (const float*)d_in[13];
    const float* b2_3 = (const float*)d_in[14];
    const float* wfc  = (const float*)d_in[15];
    const float* bfc  = (const float*)d_in[16];
    float* out = (float*)d_out;

    char* ws = (char*)d_ws;
    size_t off = 0;
    auto alloc = [&](size_t bytes) {
        void* p = ws + off;
        off = (off + bytes + 255) & ~(size_t)255;
        return p;
    };
    int* deg      = (int*)alloc((size_t)NNODES * 4);
    int* cursor   = (int*)alloc((size_t)NNODES * 4);
    int* rowptr   = (int*)alloc((size_t)(NNODES + 1) * 4);
    int* bsum     = (int*)alloc(256 * 4);
    int* boff     = (int*)alloc(256 * 4);
    int* csr_src  = (int*)alloc((size_t)NEDGES * 4);
    int* csr_dst  = (int*)alloc((size_t)NEDGES * 4);
    float* U      = (float*)alloc((size_t)NNODES * 256 * 4);
    unsigned short* V = (unsigned short*)alloc((size_t)NNODES * 256 * 2);
    float* x1     = (float*)alloc((size_t)NNODES * 64 * 4);
    float* x2     = (float*)alloc((size_t)NNODES * 128 * 4);
    float* x3     = (float*)alloc((size_t)NNODES * 256 * 4);
    unsigned* poolEnc = (unsigned*)alloc((size_t)NGRAPHS * 256 * 4);
    unsigned short* w2b2 = (unsigned short*)alloc((size_t)128 * 128 * 2);
    unsigned short* w2b3 = (unsigned short*)alloc((size_t)256 * 256 * 2);
    (void)ws_size; (void)in_sizes; (void)n_in; (void)out_size;

    // CSR by dst (shared across the 3 layers) + W2 fragment prep
    k_init<<<256, 256, 0, stream>>>(deg, cursor, poolEnc);
    k_count<<<NEDGES / 256, 256, 0, stream>>>(ei, deg);
    k_scan1<<<256, 256, 0, stream>>>(deg, rowptr, bsum);
    k_scan2<<<1, 256, 0, stream>>>(bsum, boff);
    k_scan3<<<256, 256, 0, stream>>>(rowptr, boff);
    k_scatter<<<NEDGES / 256, 256, 0, stream>>>(ei, rowptr, cursor, csr_src, csr_dst);
    k_w2prep<128, 128><<<(128 * 128) / 256, 256, 0, stream>>>(w2_2, w2b2);
    k_w2prep<256, 256><<<(256 * 256) / 256, 256, 0, stream>>>(w2_3, w2b3);

    // layer 1: F_in=3, H=64, F=64   (scalar k_uv; 16x16 k_agg, NPG=32)
    k_uv<3, 64><<<NNODES / 16, 256, 0, stream>>>(x, w1_1, b1_1, U, V);
    k_agg<64, 64, 2, 2, 32><<<NNODES / 32, 256, 0, stream>>>(U, V, w2_1, b2_1, rowptr, csr_src, csr_dst, x1);
    // layer 2: F_in=64, H=128 — MFMA k_uv; 32x32 k_agg RWAVES=1 (256 thr, 34 KB -> 4 blocks/CU)
    k_uv_mfma<64, 128><<<NNODES / 256, 512, 0, stream>>>(x1, w1_2, b1_2, U, V);
    k_agg32<128, 128, 1, 32><<<NNODES / 32, 256, 0, stream>>>(U, V, w2b2, b2_2, rowptr, csr_src, csr_dst, x2);
    // layer 3: F_in=128, H=256 — MFMA k_uv; 32x32 k_agg RWAVES=1 (512 thr, 65 KB -> 2 blocks/CU)
    k_uv_mfma<128, 256><<<NNODES / 256, 1024, 0, stream>>>(x2, w1_3, b1_3, U, V);
    k_agg32<256, 256, 1, 32><<<NNODES / 32, 512, 0, stream>>>(U, V, w2b3, b2_3, rowptr, csr_src, csr_dst, x3);

    // global max pool + FC
    k_pool<<<dim3(NGRAPHS, 8), 256, 0, stream>>>(x3, batch, poolEnc);
    k_fc<<<NGRAPHS, 128, 0, stream>>>(poolEnc, wfc, bfc, out);
}

// Round 19
// 683.261 us; speedup vs baseline: 1.1443x; 1.1443x over previous
//
#include <hip/hip_runtime.h>
#include <hip/hip_bf16.h>
#include <math.h>

#define NNODES 65536
#define NEDGES 1048576
#define NGRAPHS 64

typedef __attribute__((ext_vector_type(8))) short short8;
typedef __attribute__((ext_vector_type(4))) float f32x4;
typedef __attribute__((ext_vector_type(16))) float f32x16;

// ---- order-preserving float<->uint encoding for atomicMax-based max ----
__device__ __forceinline__ unsigned encf(float f) {
    unsigned u = __float_as_uint(f);
    return (u & 0x80000000u) ? ~u : (u | 0x80000000u);
}
__device__ __forceinline__ float decf(unsigned u) {
    unsigned v = (u & 0x80000000u) ? (u & 0x7FFFFFFFu) : ~u;
    return __uint_as_float(v);
}
#define ENC_NEG_INF 0x007FFFFFu   // encf(-inf)

// RNE float -> bf16 bits (finite values only)
__device__ __forceinline__ unsigned bfbits(float f) {
    unsigned u = __float_as_uint(f);
    return (u + 0x7FFFu + ((u >> 16) & 1u)) >> 16;
}
__device__ __forceinline__ float bfval(unsigned bits) { return __uint_as_float(bits << 16); }
// HOT path: HW packed RNE convert (1 VALU op / 2 elems). Round-8 lesson:
// __float2bfloat16 is NOT RNE on this toolchain; v_cvt_pk_bf16_f32 is RNE
// in HW and matches bfbits (verified passing rounds 10-17).
__device__ __forceinline__ unsigned pk2(float a, float b) {
    unsigned r;
    asm("v_cvt_pk_bf16_f32 %0, %1, %2" : "=v"(r) : "v"(a), "v"(b));
    return r;   // a -> low 16, b -> high 16
}
__device__ __forceinline__ float bflo(unsigned p) { return __uint_as_float(p << 16); }
__device__ __forceinline__ float bfhi(unsigned p) { return __uint_as_float(p & 0xFFFF0000u); }

// ============================ CSR build ============================
__global__ void k_init(int* deg, int* cursor, unsigned* poolEnc) {
    int i = blockIdx.x * 256 + threadIdx.x;
    if (i < NNODES) { deg[i] = 0; cursor[i] = 0; }
    if (i < NGRAPHS * 256) poolEnc[i] = ENC_NEG_INF;
}

__global__ void k_count(const int* __restrict__ ei, int* deg) {
    int e = blockIdx.x * 256 + threadIdx.x;
    atomicAdd(&deg[ei[NEDGES + e]], 1);
}

__global__ void k_scan1(const int* __restrict__ deg, int* rowptr, int* bsum) {
    __shared__ int s[256];
    int t = threadIdx.x, b = blockIdx.x;
    int v = deg[b * 256 + t];
    s[t] = v;
    __syncthreads();
    for (int off = 1; off < 256; off <<= 1) {
        int x = (t >= off) ? s[t - off] : 0;
        __syncthreads();
        if (t >= off) s[t] += x;
        __syncthreads();
    }
    rowptr[b * 256 + t] = s[t] - v;       // local exclusive
    if (t == 255) bsum[b] = s[255];
}

__global__ void k_scan2(const int* __restrict__ bsum, int* boff) {
    __shared__ int s[256];
    int t = threadIdx.x;
    int v = bsum[t];
    s[t] = v;
    __syncthreads();
    for (int off = 1; off < 256; off <<= 1) {
        int x = (t >= off) ? s[t - off] : 0;
        __syncthreads();
        if (t >= off) s[t] += x;
        __syncthreads();
    }
    boff[t] = s[t] - v;                   // exclusive block offsets
}

__global__ void k_scan3(int* rowptr, const int* __restrict__ boff) {
    int i = blockIdx.x * 256 + threadIdx.x;
    rowptr[i] += boff[blockIdx.x];
    if (i == 0) rowptr[NNODES] = NEDGES;
}

__global__ void k_scatter(const int* __restrict__ ei, const int* __restrict__ rowptr,
                          int* cursor, int* csr_src, int* csr_dst) {
    int e = blockIdx.x * 256 + threadIdx.x;
    int s = ei[e], d = ei[NEDGES + e];
    int pos = rowptr[d] + atomicAdd(&cursor[d], 1);
    csr_src[pos] = s;
    csr_dst[pos] = d;
}

// ============ W2 -> bf16 fragment-ordered prep (for k_agg32's B loads) ============
// W2b[((cw*KS16+ks)*64 + lane)*8 + j] = bf16(W2[k][col]),
// k = ks*16 + (lane>>5)*8 + j, col = cw*32 + (lane&31).
// One coalesced 16B/lane global load per (wave,ks) inside k_agg32 — W2 stays
// L2-resident (128 KB) so the B-operand costs ZERO registers.
template <int H, int F>
__global__ __launch_bounds__(256) void k_w2prep(const float* __restrict__ W2,
                                                unsigned short* __restrict__ W2b) {
    constexpr int KS16 = H / 16;
    int o = blockIdx.x * 256 + threadIdx.x;       // over H*F outputs
    int j = o & 7;
    int lane = (o >> 3) & 63;
    int t = o >> 9;
    int ks = t % KS16;
    int cw = t / KS16;
    int k = ks * 16 + (lane >> 5) * 8 + j;
    int col = cw * 32 + (lane & 31);
    W2b[o] = (unsigned short)bfbits(W2[(size_t)k * F + col]);
}

// ============================ U/V precompute ============================
// Scalar VALU version — kept for layer 1 only (FIN=3: no MFMA fit).
template <int FIN, int H>
__global__ __launch_bounds__(256) void k_uv(const float* __restrict__ X,
                                            const float* __restrict__ W1,
                                            const float* __restrict__ B1,
                                            float* __restrict__ U,
                                            unsigned short* __restrict__ Vb) {
    constexpr int NPT = (16 * H) / 256;   // nodes per thread
    __shared__ float xs[16][FIN];
    int tid = threadIdx.x;
    int n0 = blockIdx.x * 16;
    for (int idx = tid; idx < 16 * FIN; idx += 256)
        xs[idx / FIN][idx % FIN] = X[(size_t)(n0 + idx / FIN) * FIN + (idx % FIN)];
    __syncthreads();
    int h = tid & (H - 1);
    int nb = (tid / H) * NPT;
    float u[NPT], v[NPT];
    float bb = B1[h];
#pragma unroll
    for (int n = 0; n < NPT; n++) { u[n] = bb; v[n] = 0.f; }
    for (int f = 0; f < FIN; f++) {
        float wt = W1[f * H + h];
        float wb = W1[(FIN + f) * H + h];
        float wd = wt - wb;
#pragma unroll
        for (int n = 0; n < NPT; n++) {
            float xv = xs[nb + n][f];
            u[n] += xv * wd;
            v[n] += xv * wb;
        }
    }
#pragma unroll
    for (int n = 0; n < NPT; n++) {
        U[(size_t)(n0 + nb + n) * H + h] = u[n];
        Vb[(size_t)(n0 + nb + n) * H + h] = (unsigned short)bfbits(v[n]);
    }
}

// ==================== U/V precompute via MFMA (layers 2,3) ====================
// Split precision (verified round 12): S = Xhi@Whi + Xhi@Wlo + Xlo@Whi.
template <int FIN, int H>
__global__ __launch_bounds__((H / 16) * 64)
void k_uv_mfma(const float* __restrict__ X,
               const float* __restrict__ W1,
               const float* __restrict__ B1,
               float* __restrict__ U,
               unsigned short* __restrict__ Vb) {
    constexpr int WAVES = H / 16;
    constexpr int BLOCK = WAVES * 64;
    constexpr int KS = FIN / 32;          // k-steps
    constexpr int NPB = 16;               // node-tiles (of 16) per block
    constexpr int FP = FIN + 8;           // padded LDS row (bf16 units)
    static_assert(FIN % 32 == 0 && (16 * FIN) % (2 * BLOCK) == 0, "shape");

    __shared__ unsigned short xhi[16 * FP];
    __shared__ unsigned short xlo[16 * FP];

    int tid = threadIdx.x;
    int ln = tid & 15;
    int qd = (tid >> 4) & 3;
    int wv = tid >> 6;
    int col = wv * 16 + ln;

    short8 bth[KS], btl[KS], bbh[KS], bbl[KS];
#pragma unroll
    for (int ks = 0; ks < KS; ks++) {
        int kb = ks * 32 + qd * 8;
        short8 th, tl, bh, bl;
#pragma unroll
        for (int j = 0; j < 8; j++) {
            float wt = W1[(size_t)(kb + j) * H + col];
            float wb = W1[(size_t)(FIN + kb + j) * H + col];
            unsigned thb = bfbits(wt), bhb = bfbits(wb);
            th[j] = (short)thb;
            bh[j] = (short)bhb;
            tl[j] = (short)bfbits(wt - bfval(thb));
            bl[j] = (short)bfbits(wb - bfval(bhb));
        }
        bth[ks] = th; btl[ks] = tl; bbh[ks] = bh; bbl[ks] = bl;
    }

    float bias = B1[col];
    int nbase0 = blockIdx.x * (NPB * 16);

    int sidx = tid * 2;
    int snode = sidx / FIN;               // 0..15
    int sf = sidx % FIN;

    float2 xr = *(const float2*)&X[(size_t)(nbase0 + snode) * FIN + sf];

    for (int t = 0; t < NPB; t++) {
        unsigned h0 = bfbits(xr.x), h1 = bfbits(xr.y);
        unsigned l0 = bfbits(xr.x - bfval(h0));
        unsigned l1 = bfbits(xr.y - bfval(h1));
        *(unsigned*)&xhi[snode * FP + sf] = h0 | (h1 << 16);
        *(unsigned*)&xlo[snode * FP + sf] = l0 | (l1 << 16);
        if (t + 1 < NPB)
            xr = *(const float2*)&X[(size_t)(nbase0 + (t + 1) * 16 + snode) * FIN + sf];
        __syncthreads();

        f32x4 at = (f32x4){0.f, 0.f, 0.f, 0.f};
        f32x4 ab = (f32x4){0.f, 0.f, 0.f, 0.f};
#pragma unroll
        for (int ks = 0; ks < KS; ks++) {
            int ko = ks * 32 + qd * 8;
            short8 ah = *(const short8*)&xhi[ln * FP + ko];
            short8 al = *(const short8*)&xlo[ln * FP + ko];
            at = __builtin_amdgcn_mfma_f32_16x16x32_bf16(ah, bth[ks], at, 0, 0, 0);
            at = __builtin_amdgcn_mfma_f32_16x16x32_bf16(ah, btl[ks], at, 0, 0, 0);
            at = __builtin_amdgcn_mfma_f32_16x16x32_bf16(al, bth[ks], at, 0, 0, 0);
            ab = __builtin_amdgcn_mfma_f32_16x16x32_bf16(ah, bbh[ks], ab, 0, 0, 0);
            ab = __builtin_amdgcn_mfma_f32_16x16x32_bf16(ah, bbl[ks], ab, 0, 0, 0);
            ab = __builtin_amdgcn_mfma_f32_16x16x32_bf16(al, bbh[ks], ab, 0, 0, 0);
        }

        int nb = nbase0 + t * 16 + qd * 4;
#pragma unroll
        for (int j = 0; j < 4; j++) {
            U[(size_t)(nb + j) * H + col] = at[j] - ab[j] + bias;   // X@(Wt-Wb)+b
            Vb[(size_t)(nb + j) * H + col] = (unsigned short)bfbits(ab[j]); // X@Wb
        }
        __syncthreads();   // tile consumed before next overwrite
    }
}

// ================= fused edge-GEMM (MFMA bf16 16x16) + segment-max =================
// Verified round-13 version — layer 1. Round-5 pipeline + pk2 asm + NPG.
template <int H, int F, int RWAVES, int CWAVES, int NPG>
__global__ __launch_bounds__(RWAVES * CWAVES * 64)
void k_agg(const float* __restrict__ U,
           const unsigned short* __restrict__ Vb,
           const float* __restrict__ W2,
           const float* __restrict__ B2,
           const int* __restrict__ rowptr,
           const int* __restrict__ csr_src,
           const int* __restrict__ csr_dst,
           float* __restrict__ Y) {
    constexpr int BLOCK = RWAVES * CWAVES * 64;
    constexpr int TR = 32 * RWAVES;         // edge rows per tile
    constexpr int HP = H + 8;               // padded row (bf16 units), 16B-aligned frags
    constexpr int CPW = F / CWAVES;         // cols per wave
    constexpr int NT = CPW / 16;            // n-tiles per wave
    constexpr int KS = H / 32;              // k-steps
    constexpr int ACCSTR = F + 1;           // bank-spread accumulator stride
    constexpr int LPR = H / 8;              // threads per hidden row (8 elems each)
    constexpr int RPP = BLOCK / LPR;        // rows per construction pass
    constexpr int NPASS = TR / RPP;         // construction passes per tile
    static_assert(H % 32 == 0 && NT >= 1 && RPP >= 1 && TR % RPP == 0, "shape");
    static_assert(NPG <= 120, "slot fits signed char");

    __shared__ unsigned short hs[2][TR * HP];   // double-buffered hidden tile
    __shared__ unsigned accs[NPG * ACCSTR];     // per-slot running max (encoded)
    __shared__ int srcA[2][TR];
    __shared__ __align__(4) signed char slotB[2][TR];

    int tid = threadIdx.x;
    int n0 = blockIdx.x * NPG;

    int ln = tid & 15;              // MFMA n/m lane index
    int qd = (tid >> 4) & 3;        // MFMA quad
    int wv = tid >> 6;
    int rw = wv / CWAVES;           // row group
    int cw = wv % CWAVES;           // col wave

    short8 Bf[NT][KS];
#pragma unroll
    for (int nt = 0; nt < NT; nt++) {
        int col = cw * CPW + nt * 16 + ln;
#pragma unroll
        for (int ks = 0; ks < KS; ks++) {
            int kb = ks * 32 + qd * 8;
            short8 b;
#pragma unroll
            for (int j = 0; j < 8; j++)
                b[j] = (short)bfbits(W2[(size_t)(kb + j) * F + col]);
            Bf[nt][ks] = b;
        }
    }

    for (int idx = tid; idx < NPG * ACCSTR; idx += BLOCK) accs[idx] = ENC_NEG_INF;

    int e0 = rowptr[n0], e1 = rowptr[n0 + NPG];
    int ntile = (e1 - e0 + TR - 1) / TR;

    int rid = tid / LPR;            // construction: my row within a pass
    int kk = (tid % LPR) * 8;       // construction: my 8-elem chunk

    if (tid < TR) {
        int p = e0 + tid;
        int s = 0; signed char sl = -1;
        if (p < e1) { s = csr_src[p]; sl = (signed char)(csr_dst[p] - n0); }
        srcA[0][tid] = s; slotB[0][tid] = sl;
    }
    __syncthreads();

    auto mfma_tile = [&](int buf, char4 s0, char4 s1) {
        f32x4 acc[2][NT];
#pragma unroll
        for (int mt = 0; mt < 2; mt++)
#pragma unroll
            for (int nt = 0; nt < NT; nt++)
                acc[mt][nt] = (f32x4){0.f, 0.f, 0.f, 0.f};

#pragma unroll
        for (int ks = 0; ks < KS; ks++) {
            int ko = ks * 32 + qd * 8;
            short8 a0 = *(const short8*)&hs[buf][(rw * 32 + ln) * HP + ko];
            short8 a1 = *(const short8*)&hs[buf][(rw * 32 + 16 + ln) * HP + ko];
#pragma unroll
            for (int nt = 0; nt < NT; nt++) {
                acc[0][nt] = __builtin_amdgcn_mfma_f32_16x16x32_bf16(a0, Bf[nt][ks], acc[0][nt], 0, 0, 0);
                acc[1][nt] = __builtin_amdgcn_mfma_f32_16x16x32_bf16(a1, Bf[nt][ks], acc[1][nt], 0, 0, 0);
            }
        }

#pragma unroll
        for (int mt = 0; mt < 2; mt++) {
            char4 ss = mt ? s1 : s0;
#pragma unroll
            for (int nt = 0; nt < NT; nt++) {
                int colw = cw * CPW + nt * 16 + ln;
                float c0 = acc[mt][nt][0], c1 = acc[mt][nt][1];
                float c2 = acc[mt][nt][2], c3 = acc[mt][nt][3];
                float m3 = c3;
                float m2 = (ss.z == ss.w) ? fmaxf(c2, m3) : c2;
                float m1 = (ss.y == ss.z) ? fmaxf(c1, m2) : c1;
                float m0 = (ss.x == ss.y) ? fmaxf(c0, m1) : c0;
                if (ss.x >= 0)                 atomicMax(&accs[(int)ss.x * ACCSTR + colw], encf(m0));
                if (ss.y >= 0 && ss.y != ss.x) atomicMax(&accs[(int)ss.y * ACCSTR + colw], encf(m1));
                if (ss.z >= 0 && ss.z != ss.y) atomicMax(&accs[(int)ss.z * ACCSTR + colw], encf(m2));
                if (ss.w >= 0 && ss.w != ss.z) atomicMax(&accs[(int)ss.w * ACCSTR + colw], encf(m3));
            }
        }
    };

    char4 ssp0 = make_char4(-1, -1, -1, -1), ssp1 = make_char4(-1, -1, -1, -1);
    int prevbuf = 0;

    for (int t = 0; t < ntile; t++) {
        int cur = t & 1;

        int msrc[NPASS]; int msl[NPASS];
#pragma unroll
        for (int ps = 0; ps < NPASS; ps++) {
            int r = ps * RPP + rid;
            msrc[ps] = srcA[cur][r];
            msl[ps] = slotB[cur][r];
        }
        uint4 vreg[NPASS];
#pragma unroll
        for (int ps = 0; ps < NPASS; ps++)
            vreg[ps] = *(const uint4*)&Vb[(size_t)msrc[ps] * H + kk];   // src=0 for pad rows: safe
        char4 ssc0 = *(const char4*)&slotB[cur][rw * 32 + qd * 4];
        char4 ssc1 = *(const char4*)&slotB[cur][rw * 32 + 16 + qd * 4];

        int nsrc = 0; signed char nsl = -1;
        bool hn = (t + 1 < ntile);
        if (hn && tid < TR) {
            int p = e0 + (t + 1) * TR + tid;
            if (p < e1) { nsrc = csr_src[p]; nsl = (signed char)(csr_dst[p] - n0); }
        }

        if (t > 0) mfma_tile(prevbuf, ssp0, ssp1);

#pragma unroll
        for (int ps = 0; ps < NPASS; ps++) {
            int r = ps * RPP + rid;
            uint4 w;
            if (msl[ps] >= 0) {
                const float4 ua = *(const float4*)&U[(size_t)(n0 + msl[ps]) * H + kk];
                const float4 ub = *(const float4*)&U[(size_t)(n0 + msl[ps]) * H + kk + 4];
                const uint4 vv = vreg[ps];
                w.x = pk2(fmaxf(ua.x + bflo(vv.x), 0.f), fmaxf(ua.y + bfhi(vv.x), 0.f));
                w.y = pk2(fmaxf(ua.z + bflo(vv.y), 0.f), fmaxf(ua.w + bfhi(vv.y), 0.f));
                w.z = pk2(fmaxf(ub.x + bflo(vv.z), 0.f), fmaxf(ub.y + bfhi(vv.z), 0.f));
                w.w = pk2(fmaxf(ub.z + bflo(vv.w), 0.f), fmaxf(ub.w + bfhi(vv.w), 0.f));
            } else {
                w = (uint4){0u, 0u, 0u, 0u};
            }
            *(uint4*)&hs[cur][r * HP + kk] = w;
        }

        if (hn && tid < TR) { srcA[cur ^ 1][tid] = nsrc; slotB[cur ^ 1][tid] = nsl; }

        __syncthreads();
        ssp0 = ssc0; ssp1 = ssc1; prevbuf = cur;
    }
    if (ntile > 0) mfma_tile(prevbuf, ssp0, ssp1);
    __syncthreads();

    for (int idx = tid; idx < NPG * F; idx += BLOCK) {
        int sl = idx / F, cc = idx % F;
        float m = decf(accs[sl * ACCSTR + cc]);
        float o = isfinite(m) ? (m + B2[cc]) : 0.f;   // empty segment -> 0
        Y[(size_t)(n0 + sl) * F + cc] = o;
    }
}

// ============ fused edge-GEMM (MFMA bf16 32x32) + segment-max — layers 2,3 ============
// 32x32x16 MFMA (conflicts=0, A-redundancy F/32), B streamed from L2
// (fragment-ordered W2b, zero B-registers — round-17 verified, no spill).
// Round-18 lesson: RWAVES=1 (TR=32) REGRESSED (+26%): per-tile fixed costs
// (stage/barrier/B-stream per wave) doubled and the hoped 2-block overlap
// never materialized (occupancy halved). Round-19: keep round-17 geometry
// (RWAVES=2, TR=64) and halve per-block overheads via NPG=64 on layer 3
// (tail-pad waste, prologue/epilogue, accs-init amortize over 2x edges).
template <int H, int F, int RWAVES, int NPG>
__global__ __launch_bounds__(RWAVES * (F / 32) * 64)
void k_agg32(const float* __restrict__ U,
             const unsigned short* __restrict__ Vb,
             const unsigned short* __restrict__ W2b,
             const float* __restrict__ B2,
             const int* __restrict__ rowptr,
             const int* __restrict__ csr_src,
             const int* __restrict__ csr_dst,
             float* __restrict__ Y) {
    constexpr int CWAVES = F / 32;
    constexpr int BLOCK = RWAVES * CWAVES * 64;
    constexpr int TR = 32 * RWAVES;         // edge rows per tile
    constexpr int HP = H + 8;               // padded row (bf16), 16B-aligned
    constexpr int KS16 = H / 16;            // k-steps of 16
    constexpr int ACCSTR = F + 1;
    constexpr int LPR = H / 8;
    constexpr int RPP = BLOCK / LPR;
    constexpr int NPASS = TR / RPP;
    static_assert(H % 16 == 0 && TR % RPP == 0 && NPG <= 120, "shape");

    __shared__ unsigned short hs[2][TR * HP];
    __shared__ unsigned accs[NPG * ACCSTR];
    __shared__ int srcA[2][TR];
    __shared__ __align__(4) signed char slotB[2][TR];

    int tid = threadIdx.x;
    int n0 = blockIdx.x * NPG;

    int ln32 = tid & 31;            // MFMA row/col lane
    int kh = (tid >> 5) & 1;        // k-octet selector
    int wv = tid >> 6;
    int rw = wv / CWAVES;           // row group
    int cw = wv % CWAVES;           // col wave

    // per-lane base into fragment-ordered W2b: frag(cw,ks) at ((cw*KS16+ks)*64+lane)*8
    const unsigned short* Bp = W2b + ((size_t)(cw * KS16) * 64 + (tid & 63)) * 8;

    for (int idx = tid; idx < NPG * ACCSTR; idx += BLOCK) accs[idx] = ENC_NEG_INF;

    int e0 = rowptr[n0], e1 = rowptr[n0 + NPG];
    int ntile = (e1 - e0 + TR - 1) / TR;

    int rid = tid / LPR;
    int kk = (tid % LPR) * 8;

    if (tid < TR) {
        int p = e0 + tid;
        int s = 0; signed char sl = -1;
        if (p < e1) { s = csr_src[p]; sl = (signed char)(csr_dst[p] - n0); }
        srcA[0][tid] = s; slotB[0][tid] = sl;
    }
    __syncthreads();

    // MFMA + segmented max for one completed tile (B-frags streamed from L2)
    auto mfma_tile = [&](int buf, char4 sA, char4 sB, char4 sC, char4 sD) {
        f32x16 acc;
#pragma unroll
        for (int j = 0; j < 16; j++) acc[j] = 0.f;

#pragma unroll
        for (int ks = 0; ks < KS16; ks++) {
            short8 a = *(const short8*)&hs[buf][(rw * 32 + ln32) * HP + ks * 16 + kh * 8];
            short8 b = *(const short8*)&Bp[(size_t)ks * 64 * 8];
            acc = __builtin_amdgcn_mfma_f32_32x32x16_bf16(a, b, acc, 0, 0, 0);
        }

        int colw = cw * 32 + ln32;
#pragma unroll
        for (int rg = 0; rg < 4; rg++) {
            char4 ss = (rg == 0) ? sA : (rg == 1) ? sB : (rg == 2) ? sC : sD;
            float c0 = acc[4 * rg + 0], c1 = acc[4 * rg + 1];
            float c2 = acc[4 * rg + 2], c3 = acc[4 * rg + 3];
            float m3 = c3;
            float m2 = (ss.z == ss.w) ? fmaxf(c2, m3) : c2;
            float m1 = (ss.y == ss.z) ? fmaxf(c1, m2) : c1;
            float m0 = (ss.x == ss.y) ? fmaxf(c0, m1) : c0;
            if (ss.x >= 0)                 atomicMax(&accs[(int)ss.x * ACCSTR + colw], encf(m0));
            if (ss.y >= 0 && ss.y != ss.x) atomicMax(&accs[(int)ss.y * ACCSTR + colw], encf(m1));
            if (ss.z >= 0 && ss.z != ss.y) atomicMax(&accs[(int)ss.z * ACCSTR + colw], encf(m2));
            if (ss.w >= 0 && ss.w != ss.z) atomicMax(&accs[(int)ss.w * ACCSTR + colw], encf(m3));
        }
    };

    char4 sspA = make_char4(-1, -1, -1, -1), sspB = sspA, sspC = sspA, sspD = sspA;
    int prevbuf = 0;
    int rbase = rw * 32 + 4 * kh;   // my C-rows: rbase + 8*rg + {0..3}

    for (int t = 0; t < ntile; t++) {
        int cur = t & 1;

        // (1) tile-t metadata + EARLY V-gathers
        int msrc[NPASS]; int msl[NPASS];
#pragma unroll
        for (int ps = 0; ps < NPASS; ps++) {
            int r = ps * RPP + rid;
            msrc[ps] = srcA[cur][r];
            msl[ps] = slotB[cur][r];
        }
        uint4 vreg[NPASS];
#pragma unroll
        for (int ps = 0; ps < NPASS; ps++)
            vreg[ps] = *(const uint4*)&Vb[(size_t)msrc[ps] * H + kk];
        char4 sscA = *(const char4*)&slotB[cur][rbase + 0];
        char4 sscB = *(const char4*)&slotB[cur][rbase + 8];
        char4 sscC = *(const char4*)&slotB[cur][rbase + 16];
        char4 sscD = *(const char4*)&slotB[cur][rbase + 24];

        // (2) prefetch CSR metadata for tile t+1
        int nsrc = 0; signed char nsl = -1;
        bool hn = (t + 1 < ntile);
        if (hn && tid < TR) {
            int p = e0 + (t + 1) * TR + tid;
            if (p < e1) { nsrc = csr_src[p]; nsl = (signed char)(csr_dst[p] - n0); }
        }

        // (3) MFMA + seg-max for tile t-1
        if (t > 0) mfma_tile(prevbuf, sspA, sspB, sspC, sspD);

        // (4) build hidden tile t
#pragma unroll
        for (int ps = 0; ps < NPASS; ps++) {
            int r = ps * RPP + rid;
            uint4 w;
            if (msl[ps] >= 0) {
                const float4 ua = *(const float4*)&U[(size_t)(n0 + msl[ps]) * H + kk];
                const float4 ub = *(const float4*)&U[(size_t)(n0 + msl[ps]) * H + kk + 4];
                const uint4 vv = vreg[ps];
                w.x = pk2(fmaxf(ua.x + bflo(vv.x), 0.f), fmaxf(ua.y + bfhi(vv.x), 0.f));
                w.y = pk2(fmaxf(ua.z + bflo(vv.y), 0.f), fmaxf(ua.w + bfhi(vv.y), 0.f));
                w.z = pk2(fmaxf(ub.x + bflo(vv.z), 0.f), fmaxf(ub.y + bfhi(vv.z), 0.f));
                w.w = pk2(fmaxf(ub.z + bflo(vv.w), 0.f), fmaxf(ub.w + bfhi(vv.w), 0.f));
            } else {
                w = (uint4){0u, 0u, 0u, 0u};
            }
            *(uint4*)&hs[cur][r * HP + kk] = w;
        }

        // (5) stage next tile's CSR metadata
        if (hn && tid < TR) { srcA[cur ^ 1][tid] = nsrc; slotB[cur ^ 1][tid] = nsl; }

        // (6) one barrier per tile
        __syncthreads();
        sspA = sscA; sspB = sscB; sspC = sscC; sspD = sscD; prevbuf = cur;
    }
    if (ntile > 0) mfma_tile(prevbuf, sspA, sspB, sspC, sspD);
    __syncthreads();

    for (int idx = tid; idx < NPG * F; idx += BLOCK) {
        int sl = idx / F, cc = idx % F;
        float m = decf(accs[sl * ACCSTR + cc]);
        float o = isfinite(m) ? (m + B2[cc]) : 0.f;
        Y[(size_t)(n0 + sl) * F + cc] = o;
    }
}

// ============================ global max-pool + FC ============================
__global__ void k_pool(const float* __restrict__ X3, const int* __restrict__ batch,
                       unsigned* poolEnc) {
    int gph = blockIdx.x;
    int seg = blockIdx.y;
    int c = threadIdx.x;
    int lo = 0, hi = NNODES;
    while (lo < hi) { int mid = (lo + hi) >> 1; if (batch[mid] < gph) lo = mid + 1; else hi = mid; }
    int start = lo;
    hi = NNODES;
    while (lo < hi) { int mid = (lo + hi) >> 1; if (batch[mid] < gph + 1) lo = mid + 1; else hi = mid; }
    int end = lo;
    int chunk = (end - start + 7) >> 3;
    int s = start + seg * chunk;
    int e = min(end, s + chunk);
    float m = -INFINITY;
    for (int n = s; n < e; n++) m = fmaxf(m, X3[(size_t)n * 256 + c]);
    atomicMax(&poolEnc[gph * 256 + c], encf(m));
}

__global__ __launch_bounds__(128) void k_fc(const unsigned* __restrict__ poolEnc,
                                            const float* __restrict__ Wfc,
                                            const float* __restrict__ Bfc,
                                            float* __restrict__ out) {
    __shared__ float p[256];
    int gph = blockIdx.x, c = threadIdx.x;
    for (int k = c; k < 256; k += 128) {
        float m = decf(poolEnc[gph * 256 + k]);
        p[k] = isfinite(m) ? m : 0.f;
    }
    __syncthreads();
    float s = Bfc[c];
    for (int k = 0; k < 256; k++) s += p[k] * Wfc[k * 128 + c];
    out[gph * 128 + c] = s;
}

// ============================ launch ============================
extern "C" void kernel_launch(void* const* d_in, const int* in_sizes, int n_in,
                              void* d_out, int out_size, void* d_ws, size_t ws_size,
                              hipStream_t stream) {
    const float* x     = (const float*)d_in[0];
    const int*   ei    = (const int*)d_in[1];
    const int*   batch = (const int*)d_in[2];
    const float* w1_1 = (const float*)d_in[3];
    const float* b1_1 = (const float*)d_in[4];
    const float* w2_1 = (const float*)d_in[5];
    const float* b2_1 = (const float*)d_in[6];
    const float* w1_2 = (const float*)d_in[7];
    const float* b1_2 = (const float*)d_in[8];
    const float* w2_2 = (const float*)d_in[9];
    const float* b2_2 = (const float*)d_in[10];
    const float* w1_3 = (const float*)d_in[11];
    const float* b1_3 = (const float*)d_in[12];
    const float* w2_3 = (const float*)d_in[13];
    const float* b2_3 = (const float*)d_in[14];
    const float* wfc  = (const float*)d_in[15];
    const float* bfc  = (const float*)d_in[16];
    float* out = (float*)d_out;

    char* ws = (char*)d_ws;
    size_t off = 0;
    auto alloc = [&](size_t bytes) {
        void* p = ws + off;
        off = (off + bytes + 255) & ~(size_t)255;
        return p;
    };
    int* deg      = (int*)alloc((size_t)NNODES * 4);
    int* cursor   = (int*)alloc((size_t)NNODES * 4);
    int* rowptr   = (int*)alloc((size_t)(NNODES + 1) * 4);
    int* bsum     = (int*)alloc(256 * 4);
    int* boff     = (int*)alloc(256 * 4);
    int* csr_src  = (int*)alloc((size_t)NEDGES * 4);
    int* csr_dst  = (int*)alloc((size_t)NEDGES * 4);
    float* U      = (float*)alloc((size_t)NNODES * 256 * 4);
    unsigned short* V = (unsigned short*)alloc((size_t)NNODES * 256 * 2);
    float* x1     = (float*)alloc((size_t)NNODES * 64 * 4);
    float* x2     = (float*)alloc((size_t)NNODES * 128 * 4);
    float* x3     = (float*)alloc((size_t)NNODES * 256 * 4);
    unsigned* poolEnc = (unsigned*)alloc((size_t)NGRAPHS * 256 * 4);
    unsigned short* w2b2 = (unsigned short*)alloc((size_t)128 * 128 * 2);
    unsigned short* w2b3 = (unsigned short*)alloc((size_t)256 * 256 * 2);
    (void)ws_size; (void)in_sizes; (void)n_in; (void)out_size;

    // CSR by dst (shared across the 3 layers) + W2 fragment prep
    k_init<<<256, 256, 0, stream>>>(deg, cursor, poolEnc);
    k_count<<<NEDGES / 256, 256, 0, stream>>>(ei, deg);
    k_scan1<<<256, 256, 0, stream>>>(deg, rowptr, bsum);
    k_scan2<<<1, 256, 0, stream>>>(bsum, boff);
    k_scan3<<<256, 256, 0, stream>>>(rowptr, boff);
    k_scatter<<<NEDGES / 256, 256, 0, stream>>>(ei, rowptr, cursor, csr_src, csr_dst);
    k_w2prep<128, 128><<<(128 * 128) / 256, 256, 0, stream>>>(w2_2, w2b2);
    k_w2prep<256, 256><<<(256 * 256) / 256, 256, 0, stream>>>(w2_3, w2b3);

    // layer 1: F_in=3, H=64, F=64   (scalar k_uv; 16x16 k_agg, NPG=32)
    k_uv<3, 64><<<NNODES / 16, 256, 0, stream>>>(x, w1_1, b1_1, U, V);
    k_agg<64, 64, 2, 2, 32><<<NNODES / 32, 256, 0, stream>>>(U, V, w2_1, b2_1, rowptr, csr_src, csr_dst, x1);
    // layer 2: F_in=64, H=128 — MFMA k_uv; 32x32 k_agg RWAVES=2 (512 thr, NPG=32) [round-17 verified]
    k_uv_mfma<64, 128><<<NNODES / 256, 512, 0, stream>>>(x1, w1_2, b1_2, U, V);
    k_agg32<128, 128, 2, 32><<<NNODES / 32, 512, 0, stream>>>(U, V, w2b2, b2_2, rowptr, csr_src, csr_dst, x2);
    // layer 3: F_in=128, H=256 — MFMA k_uv; 32x32 k_agg RWAVES=2 (1024 thr), NPG=64 (134 KB LDS, 1024 blocks)
    k_uv_mfma<128, 256><<<NNODES / 256, 1024, 0, stream>>>(x2, w1_3, b1_3, U, V);
    k_agg32<256, 256, 2, 64><<<NNODES / 64, 1024, 0, stream>>>(U, V, w2b3, b2_3, rowptr, csr_src, csr_dst, x3);

    // global max pool + FC
    k_pool<<<dim3(NGRAPHS, 8), 256, 0, stream>>>(x3, batch, poolEnc);
    k_fc<<<NGRAPHS, 128, 0, stream>>>(poolEnc, wfc, bfc, out);
}

// Round 20
// 681.526 us; speedup vs baseline: 1.1472x; 1.0025x over previous
//
#include <hip/hip_runtime.h>
#include <hip/hip_bf16.h>
#include <math.h>

#define NNODES 65536
#define NEDGES 1048576
#define NGRAPHS 64

typedef __attribute__((ext_vector_type(8))) short short8;
typedef __attribute__((ext_vector_type(4))) float f32x4;
typedef __attribute__((ext_vector_type(16))) float f32x16;

// ---- order-preserving float<->uint encoding for atomicMax-based max ----
__device__ __forceinline__ unsigned encf(float f) {
    unsigned u = __float_as_uint(f);
    return (u & 0x80000000u) ? ~u : (u | 0x80000000u);
}
__device__ __forceinline__ float decf(unsigned u) {
    unsigned v = (u & 0x80000000u) ? (u & 0x7FFFFFFFu) : ~u;
    return __uint_as_float(v);
}
#define ENC_NEG_INF 0x007FFFFFu   // encf(-inf)

// RNE float -> bf16 bits (finite values only)
__device__ __forceinline__ unsigned bfbits(float f) {
    unsigned u = __float_as_uint(f);
    return (u + 0x7FFFu + ((u >> 16) & 1u)) >> 16;
}
__device__ __forceinline__ float bfval(unsigned bits) { return __uint_as_float(bits << 16); }
// HOT path: HW packed RNE convert (1 VALU op / 2 elems). Round-8 lesson:
// __float2bfloat16 is NOT RNE on this toolchain; v_cvt_pk_bf16_f32 is RNE
// in HW and matches bfbits (verified passing rounds 10-19).
__device__ __forceinline__ unsigned pk2(float a, float b) {
    unsigned r;
    asm("v_cvt_pk_bf16_f32 %0, %1, %2" : "=v"(r) : "v"(a), "v"(b));
    return r;   // a -> low 16, b -> high 16
}
__device__ __forceinline__ float bflo(unsigned p) { return __uint_as_float(p << 16); }
__device__ __forceinline__ float bfhi(unsigned p) { return __uint_as_float(p & 0xFFFF0000u); }

// ============================ CSR build ============================
__global__ void k_init(int* deg, int* cursor, unsigned* poolEnc) {
    int i = blockIdx.x * 256 + threadIdx.x;
    if (i < NNODES) { deg[i] = 0; cursor[i] = 0; }
    if (i < NGRAPHS * 256) poolEnc[i] = ENC_NEG_INF;
}

__global__ void k_count(const int* __restrict__ ei, int* deg) {
    int e = blockIdx.x * 256 + threadIdx.x;
    atomicAdd(&deg[ei[NEDGES + e]], 1);
}

__global__ void k_scan1(const int* __restrict__ deg, int* rowptr, int* bsum) {
    __shared__ int s[256];
    int t = threadIdx.x, b = blockIdx.x;
    int v = deg[b * 256 + t];
    s[t] = v;
    __syncthreads();
    for (int off = 1; off < 256; off <<= 1) {
        int x = (t >= off) ? s[t - off] : 0;
        __syncthreads();
        if (t >= off) s[t] += x;
        __syncthreads();
    }
    rowptr[b * 256 + t] = s[t] - v;       // local exclusive
    if (t == 255) bsum[b] = s[255];
}

__global__ void k_scan2(const int* __restrict__ bsum, int* boff) {
    __shared__ int s[256];
    int t = threadIdx.x;
    int v = bsum[t];
    s[t] = v;
    __syncthreads();
    for (int off = 1; off < 256; off <<= 1) {
        int x = (t >= off) ? s[t - off] : 0;
        __syncthreads();
        if (t >= off) s[t] += x;
        __syncthreads();
    }
    boff[t] = s[t] - v;                   // exclusive block offsets
}

__global__ void k_scan3(int* rowptr, const int* __restrict__ boff) {
    int i = blockIdx.x * 256 + threadIdx.x;
    rowptr[i] += boff[blockIdx.x];
    if (i == 0) rowptr[NNODES] = NEDGES;
}

__global__ void k_scatter(const int* __restrict__ ei, const int* __restrict__ rowptr,
                          int* cursor, int* csr_src, int* csr_dst) {
    int e = blockIdx.x * 256 + threadIdx.x;
    int s = ei[e], d = ei[NEDGES + e];
    int pos = rowptr[d] + atomicAdd(&cursor[d], 1);
    csr_src[pos] = s;
    csr_dst[pos] = d;
}

// ============ W2 -> bf16 fragment-ordered prep (for k_agg32's B loads) ============
// W2b[((cw*KS16+ks)*64 + lane)*8 + j] = bf16(W2[k][col]),
// k = ks*16 + (lane>>5)*8 + j, col = cw*32 + (lane&31).
// One coalesced 16B/lane global load per (wave,ks) inside k_agg32 — W2 stays
// L2-resident (128 KB) so the B-operand costs ZERO registers.
template <int H, int F>
__global__ __launch_bounds__(256) void k_w2prep(const float* __restrict__ W2,
                                                unsigned short* __restrict__ W2b) {
    constexpr int KS16 = H / 16;
    int o = blockIdx.x * 256 + threadIdx.x;       // over H*F outputs
    int j = o & 7;
    int lane = (o >> 3) & 63;
    int t = o >> 9;
    int ks = t % KS16;
    int cw = t / KS16;
    int k = ks * 16 + (lane >> 5) * 8 + j;
    int col = cw * 32 + (lane & 31);
    W2b[o] = (unsigned short)bfbits(W2[(size_t)k * F + col]);
}

// ============================ U/V precompute ============================
// Scalar VALU version — kept for layer 1 only (FIN=3: no MFMA fit).
template <int FIN, int H>
__global__ __launch_bounds__(256) void k_uv(const float* __restrict__ X,
                                            const float* __restrict__ W1,
                                            const float* __restrict__ B1,
                                            float* __restrict__ U,
                                            unsigned short* __restrict__ Vb) {
    constexpr int NPT = (16 * H) / 256;   // nodes per thread
    __shared__ float xs[16][FIN];
    int tid = threadIdx.x;
    int n0 = blockIdx.x * 16;
    for (int idx = tid; idx < 16 * FIN; idx += 256)
        xs[idx / FIN][idx % FIN] = X[(size_t)(n0 + idx / FIN) * FIN + (idx % FIN)];
    __syncthreads();
    int h = tid & (H - 1);
    int nb = (tid / H) * NPT;
    float u[NPT], v[NPT];
    float bb = B1[h];
#pragma unroll
    for (int n = 0; n < NPT; n++) { u[n] = bb; v[n] = 0.f; }
    for (int f = 0; f < FIN; f++) {
        float wt = W1[f * H + h];
        float wb = W1[(FIN + f) * H + h];
        float wd = wt - wb;
#pragma unroll
        for (int n = 0; n < NPT; n++) {
            float xv = xs[nb + n][f];
            u[n] += xv * wd;
            v[n] += xv * wb;
        }
    }
#pragma unroll
    for (int n = 0; n < NPT; n++) {
        U[(size_t)(n0 + nb + n) * H + h] = u[n];
        Vb[(size_t)(n0 + nb + n) * H + h] = (unsigned short)bfbits(v[n]);
    }
}

// ==================== U/V precompute via MFMA (layers 2,3) ====================
// Split precision (verified round 12): S = Xhi@Whi + Xhi@Wlo + Xlo@Whi.
template <int FIN, int H>
__global__ __launch_bounds__((H / 16) * 64)
void k_uv_mfma(const float* __restrict__ X,
               const float* __restrict__ W1,
               const float* __restrict__ B1,
               float* __restrict__ U,
               unsigned short* __restrict__ Vb) {
    constexpr int WAVES = H / 16;
    constexpr int BLOCK = WAVES * 64;
    constexpr int KS = FIN / 32;          // k-steps
    constexpr int NPB = 16;               // node-tiles (of 16) per block
    constexpr int FP = FIN + 8;           // padded LDS row (bf16 units)
    static_assert(FIN % 32 == 0 && (16 * FIN) % (2 * BLOCK) == 0, "shape");

    __shared__ unsigned short xhi[16 * FP];
    __shared__ unsigned short xlo[16 * FP];

    int tid = threadIdx.x;
    int ln = tid & 15;
    int qd = (tid >> 4) & 3;
    int wv = tid >> 6;
    int col = wv * 16 + ln;

    short8 bth[KS], btl[KS], bbh[KS], bbl[KS];
#pragma unroll
    for (int ks = 0; ks < KS; ks++) {
        int kb = ks * 32 + qd * 8;
        short8 th, tl, bh, bl;
#pragma unroll
        for (int j = 0; j < 8; j++) {
            float wt = W1[(size_t)(kb + j) * H + col];
            float wb = W1[(size_t)(FIN + kb + j) * H + col];
            unsigned thb = bfbits(wt), bhb = bfbits(wb);
            th[j] = (short)thb;
            bh[j] = (short)bhb;
            tl[j] = (short)bfbits(wt - bfval(thb));
            bl[j] = (short)bfbits(wb - bfval(bhb));
        }
        bth[ks] = th; btl[ks] = tl; bbh[ks] = bh; bbl[ks] = bl;
    }

    float bias = B1[col];
    int nbase0 = blockIdx.x * (NPB * 16);

    int sidx = tid * 2;
    int snode = sidx / FIN;               // 0..15
    int sf = sidx % FIN;

    float2 xr = *(const float2*)&X[(size_t)(nbase0 + snode) * FIN + sf];

    for (int t = 0; t < NPB; t++) {
        unsigned h0 = bfbits(xr.x), h1 = bfbits(xr.y);
        unsigned l0 = bfbits(xr.x - bfval(h0));
        unsigned l1 = bfbits(xr.y - bfval(h1));
        *(unsigned*)&xhi[snode * FP + sf] = h0 | (h1 << 16);
        *(unsigned*)&xlo[snode * FP + sf] = l0 | (l1 << 16);
        if (t + 1 < NPB)
            xr = *(const float2*)&X[(size_t)(nbase0 + (t + 1) * 16 + snode) * FIN + sf];
        __syncthreads();

        f32x4 at = (f32x4){0.f, 0.f, 0.f, 0.f};
        f32x4 ab = (f32x4){0.f, 0.f, 0.f, 0.f};
#pragma unroll
        for (int ks = 0; ks < KS; ks++) {
            int ko = ks * 32 + qd * 8;
            short8 ah = *(const short8*)&xhi[ln * FP + ko];
            short8 al = *(const short8*)&xlo[ln * FP + ko];
            at = __builtin_amdgcn_mfma_f32_16x16x32_bf16(ah, bth[ks], at, 0, 0, 0);
            at = __builtin_amdgcn_mfma_f32_16x16x32_bf16(ah, btl[ks], at, 0, 0, 0);
            at = __builtin_amdgcn_mfma_f32_16x16x32_bf16(al, bth[ks], at, 0, 0, 0);
            ab = __builtin_amdgcn_mfma_f32_16x16x32_bf16(ah, bbh[ks], ab, 0, 0, 0);
            ab = __builtin_amdgcn_mfma_f32_16x16x32_bf16(ah, bbl[ks], ab, 0, 0, 0);
            ab = __builtin_amdgcn_mfma_f32_16x16x32_bf16(al, bbh[ks], ab, 0, 0, 0);
        }

        int nb = nbase0 + t * 16 + qd * 4;
#pragma unroll
        for (int j = 0; j < 4; j++) {
            U[(size_t)(nb + j) * H + col] = at[j] - ab[j] + bias;   // X@(Wt-Wb)+b
            Vb[(size_t)(nb + j) * H + col] = (unsigned short)bfbits(ab[j]); // X@Wb
        }
        __syncthreads();   // tile consumed before next overwrite
    }
}

// ================= fused edge-GEMM (MFMA bf16 16x16) + segment-max =================
// Verified round-13 version — layer 1. Round-5 pipeline + pk2 asm + NPG.
// Round-20: NPG=64 (per-block overheads amortize over 2x edges; verified
// lever on L3 rounds 13/19). LDS ~54 KB @256 thr.
template <int H, int F, int RWAVES, int CWAVES, int NPG>
__global__ __launch_bounds__(RWAVES * CWAVES * 64)
void k_agg(const float* __restrict__ U,
           const unsigned short* __restrict__ Vb,
           const float* __restrict__ W2,
           const float* __restrict__ B2,
           const int* __restrict__ rowptr,
           const int* __restrict__ csr_src,
           const int* __restrict__ csr_dst,
           float* __restrict__ Y) {
    constexpr int BLOCK = RWAVES * CWAVES * 64;
    constexpr int TR = 32 * RWAVES;         // edge rows per tile
    constexpr int HP = H + 8;               // padded row (bf16 units), 16B-aligned frags
    constexpr int CPW = F / CWAVES;         // cols per wave
    constexpr int NT = CPW / 16;            // n-tiles per wave
    constexpr int KS = H / 32;              // k-steps
    constexpr int ACCSTR = F + 1;           // bank-spread accumulator stride
    constexpr int LPR = H / 8;              // threads per hidden row (8 elems each)
    constexpr int RPP = BLOCK / LPR;        // rows per construction pass
    constexpr int NPASS = TR / RPP;         // construction passes per tile
    static_assert(H % 32 == 0 && NT >= 1 && RPP >= 1 && TR % RPP == 0, "shape");
    static_assert(NPG <= 120, "slot fits signed char");

    __shared__ unsigned short hs[2][TR * HP];   // double-buffered hidden tile
    __shared__ unsigned accs[NPG * ACCSTR];     // per-slot running max (encoded)
    __shared__ int srcA[2][TR];
    __shared__ __align__(4) signed char slotB[2][TR];

    int tid = threadIdx.x;
    int n0 = blockIdx.x * NPG;

    int ln = tid & 15;              // MFMA n/m lane index
    int qd = (tid >> 4) & 3;        // MFMA quad
    int wv = tid >> 6;
    int rw = wv / CWAVES;           // row group
    int cw = wv % CWAVES;           // col wave

    short8 Bf[NT][KS];
#pragma unroll
    for (int nt = 0; nt < NT; nt++) {
        int col = cw * CPW + nt * 16 + ln;
#pragma unroll
        for (int ks = 0; ks < KS; ks++) {
            int kb = ks * 32 + qd * 8;
            short8 b;
#pragma unroll
            for (int j = 0; j < 8; j++)
                b[j] = (short)bfbits(W2[(size_t)(kb + j) * F + col]);
            Bf[nt][ks] = b;
        }
    }

    for (int idx = tid; idx < NPG * ACCSTR; idx += BLOCK) accs[idx] = ENC_NEG_INF;

    int e0 = rowptr[n0], e1 = rowptr[n0 + NPG];
    int ntile = (e1 - e0 + TR - 1) / TR;

    int rid = tid / LPR;            // construction: my row within a pass
    int kk = (tid % LPR) * 8;       // construction: my 8-elem chunk

    if (tid < TR) {
        int p = e0 + tid;
        int s = 0; signed char sl = -1;
        if (p < e1) { s = csr_src[p]; sl = (signed char)(csr_dst[p] - n0); }
        srcA[0][tid] = s; slotB[0][tid] = sl;
    }
    __syncthreads();

    auto mfma_tile = [&](int buf, char4 s0, char4 s1) {
        f32x4 acc[2][NT];
#pragma unroll
        for (int mt = 0; mt < 2; mt++)
#pragma unroll
            for (int nt = 0; nt < NT; nt++)
                acc[mt][nt] = (f32x4){0.f, 0.f, 0.f, 0.f};

#pragma unroll
        for (int ks = 0; ks < KS; ks++) {
            int ko = ks * 32 + qd * 8;
            short8 a0 = *(const short8*)&hs[buf][(rw * 32 + ln) * HP + ko];
            short8 a1 = *(const short8*)&hs[buf][(rw * 32 + 16 + ln) * HP + ko];
#pragma unroll
            for (int nt = 0; nt < NT; nt++) {
                acc[0][nt] = __builtin_amdgcn_mfma_f32_16x16x32_bf16(a0, Bf[nt][ks], acc[0][nt], 0, 0, 0);
                acc[1][nt] = __builtin_amdgcn_mfma_f32_16x16x32_bf16(a1, Bf[nt][ks], acc[1][nt], 0, 0, 0);
            }
        }

#pragma unroll
        for (int mt = 0; mt < 2; mt++) {
            char4 ss = mt ? s1 : s0;
#pragma unroll
            for (int nt = 0; nt < NT; nt++) {
                int colw = cw * CPW + nt * 16 + ln;
                float c0 = acc[mt][nt][0], c1 = acc[mt][nt][1];
                float c2 = acc[mt][nt][2], c3 = acc[mt][nt][3];
                float m3 = c3;
                float m2 = (ss.z == ss.w) ? fmaxf(c2, m3) : c2;
                float m1 = (ss.y == ss.z) ? fmaxf(c1, m2) : c1;
                float m0 = (ss.x == ss.y) ? fmaxf(c0, m1) : c0;
                if (ss.x >= 0)                 atomicMax(&accs[(int)ss.x * ACCSTR + colw], encf(m0));
                if (ss.y >= 0 && ss.y != ss.x) atomicMax(&accs[(int)ss.y * ACCSTR + colw], encf(m1));
                if (ss.z >= 0 && ss.z != ss.y) atomicMax(&accs[(int)ss.z * ACCSTR + colw], encf(m2));
                if (ss.w >= 0 && ss.w != ss.z) atomicMax(&accs[(int)ss.w * ACCSTR + colw], encf(m3));
            }
        }
    };

    char4 ssp0 = make_char4(-1, -1, -1, -1), ssp1 = make_char4(-1, -1, -1, -1);
    int prevbuf = 0;

    for (int t = 0; t < ntile; t++) {
        int cur = t & 1;

        int msrc[NPASS]; int msl[NPASS];
#pragma unroll
        for (int ps = 0; ps < NPASS; ps++) {
            int r = ps * RPP + rid;
            msrc[ps] = srcA[cur][r];
            msl[ps] = slotB[cur][r];
        }
        uint4 vreg[NPASS];
#pragma unroll
        for (int ps = 0; ps < NPASS; ps++)
            vreg[ps] = *(const uint4*)&Vb[(size_t)msrc[ps] * H + kk];   // src=0 for pad rows: safe
        char4 ssc0 = *(const char4*)&slotB[cur][rw * 32 + qd * 4];
        char4 ssc1 = *(const char4*)&slotB[cur][rw * 32 + 16 + qd * 4];

        int nsrc = 0; signed char nsl = -1;
        bool hn = (t + 1 < ntile);
        if (hn && tid < TR) {
            int p = e0 + (t + 1) * TR + tid;
            if (p < e1) { nsrc = csr_src[p]; nsl = (signed char)(csr_dst[p] - n0); }
        }

        if (t > 0) mfma_tile(prevbuf, ssp0, ssp1);

#pragma unroll
        for (int ps = 0; ps < NPASS; ps++) {
            int r = ps * RPP + rid;
            uint4 w;
            if (msl[ps] >= 0) {
                const float4 ua = *(const float4*)&U[(size_t)(n0 + msl[ps]) * H + kk];
                const float4 ub = *(const float4*)&U[(size_t)(n0 + msl[ps]) * H + kk + 4];
                const uint4 vv = vreg[ps];
                w.x = pk2(fmaxf(ua.x + bflo(vv.x), 0.f), fmaxf(ua.y + bfhi(vv.x), 0.f));
                w.y = pk2(fmaxf(ua.z + bflo(vv.y), 0.f), fmaxf(ua.w + bfhi(vv.y), 0.f));
                w.z = pk2(fmaxf(ub.x + bflo(vv.z), 0.f), fmaxf(ub.y + bfhi(vv.z), 0.f));
                w.w = pk2(fmaxf(ub.z + bflo(vv.w), 0.f), fmaxf(ub.w + bfhi(vv.w), 0.f));
            } else {
                w = (uint4){0u, 0u, 0u, 0u};
            }
            *(uint4*)&hs[cur][r * HP + kk] = w;
        }

        if (hn && tid < TR) { srcA[cur ^ 1][tid] = nsrc; slotB[cur ^ 1][tid] = nsl; }

        __syncthreads();
        ssp0 = ssc0; ssp1 = ssc1; prevbuf = cur;
    }
    if (ntile > 0) mfma_tile(prevbuf, ssp0, ssp1);
    __syncthreads();

    for (int idx = tid; idx < NPG * F; idx += BLOCK) {
        int sl = idx / F, cc = idx % F;
        float m = decf(accs[sl * ACCSTR + cc]);
        float o = isfinite(m) ? (m + B2[cc]) : 0.f;   // empty segment -> 0
        Y[(size_t)(n0 + sl) * F + cc] = o;
    }
}

// ============ fused edge-GEMM (MFMA bf16 32x32) + segment-max — layers 2,3 ============
// 32x32x16 MFMA (conflicts=0, A-redundancy F/32), B streamed from L2
// (fragment-ordered W2b, zero B-registers — round-17 verified, no spill).
// RWAVES=2 / TR=64 (round-18: smaller tiles regressed). NPG amortizes
// per-block overheads (rounds 13/19 verified): L3 NPG=64 (134 KB LDS),
// L2 NPG=64 (68.5 KB LDS).
template <int H, int F, int RWAVES, int NPG>
__global__ __launch_bounds__(RWAVES * (F / 32) * 64)
void k_agg32(const float* __restrict__ U,
             const unsigned short* __restrict__ Vb,
             const unsigned short* __restrict__ W2b,
             const float* __restrict__ B2,
             const int* __restrict__ rowptr,
             const int* __restrict__ csr_src,
             const int* __restrict__ csr_dst,
             float* __restrict__ Y) {
    constexpr int CWAVES = F / 32;
    constexpr int BLOCK = RWAVES * CWAVES * 64;
    constexpr int TR = 32 * RWAVES;         // edge rows per tile
    constexpr int HP = H + 8;               // padded row (bf16), 16B-aligned
    constexpr int KS16 = H / 16;            // k-steps of 16
    constexpr int ACCSTR = F + 1;
    constexpr int LPR = H / 8;
    constexpr int RPP = BLOCK / LPR;
    constexpr int NPASS = TR / RPP;
    static_assert(H % 16 == 0 && TR % RPP == 0 && NPG <= 120, "shape");

    __shared__ unsigned short hs[2][TR * HP];
    __shared__ unsigned accs[NPG * ACCSTR];
    __shared__ int srcA[2][TR];
    __shared__ __align__(4) signed char slotB[2][TR];

    int tid = threadIdx.x;
    int n0 = blockIdx.x * NPG;

    int ln32 = tid & 31;            // MFMA row/col lane
    int kh = (tid >> 5) & 1;        // k-octet selector
    int wv = tid >> 6;
    int rw = wv / CWAVES;           // row group
    int cw = wv % CWAVES;           // col wave

    // per-lane base into fragment-ordered W2b: frag(cw,ks) at ((cw*KS16+ks)*64+lane)*8
    const unsigned short* Bp = W2b + ((size_t)(cw * KS16) * 64 + (tid & 63)) * 8;

    for (int idx = tid; idx < NPG * ACCSTR; idx += BLOCK) accs[idx] = ENC_NEG_INF;

    int e0 = rowptr[n0], e1 = rowptr[n0 + NPG];
    int ntile = (e1 - e0 + TR - 1) / TR;

    int rid = tid / LPR;
    int kk = (tid % LPR) * 8;

    if (tid < TR) {
        int p = e0 + tid;
        int s = 0; signed char sl = -1;
        if (p < e1) { s = csr_src[p]; sl = (signed char)(csr_dst[p] - n0); }
        srcA[0][tid] = s; slotB[0][tid] = sl;
    }
    __syncthreads();

    // MFMA + segmented max for one completed tile (B-frags streamed from L2)
    auto mfma_tile = [&](int buf, char4 sA, char4 sB, char4 sC, char4 sD) {
        f32x16 acc;
#pragma unroll
        for (int j = 0; j < 16; j++) acc[j] = 0.f;

#pragma unroll
        for (int ks = 0; ks < KS16; ks++) {
            short8 a = *(const short8*)&hs[buf][(rw * 32 + ln32) * HP + ks * 16 + kh * 8];
            short8 b = *(const short8*)&Bp[(size_t)ks * 64 * 8];
            acc = __builtin_amdgcn_mfma_f32_32x32x16_bf16(a, b, acc, 0, 0, 0);
        }

        int colw = cw * 32 + ln32;
#pragma unroll
        for (int rg = 0; rg < 4; rg++) {
            char4 ss = (rg == 0) ? sA : (rg == 1) ? sB : (rg == 2) ? sC : sD;
            float c0 = acc[4 * rg + 0], c1 = acc[4 * rg + 1];
            float c2 = acc[4 * rg + 2], c3 = acc[4 * rg + 3];
            float m3 = c3;
            float m2 = (ss.z == ss.w) ? fmaxf(c2, m3) : c2;
            float m1 = (ss.y == ss.z) ? fmaxf(c1, m2) : c1;
            float m0 = (ss.x == ss.y) ? fmaxf(c0, m1) : c0;
            if (ss.x >= 0)                 atomicMax(&accs[(int)ss.x * ACCSTR + colw], encf(m0));
            if (ss.y >= 0 && ss.y != ss.x) atomicMax(&accs[(int)ss.y * ACCSTR + colw], encf(m1));
            if (ss.z >= 0 && ss.z != ss.y) atomicMax(&accs[(int)ss.z * ACCSTR + colw], encf(m2));
            if (ss.w >= 0 && ss.w != ss.z) atomicMax(&accs[(int)ss.w * ACCSTR + colw], encf(m3));
        }
    };

    char4 sspA = make_char4(-1, -1, -1, -1), sspB = sspA, sspC = sspA, sspD = sspA;
    int prevbuf = 0;
    int rbase = rw * 32 + 4 * kh;   // my C-rows: rbase + 8*rg + {0..3}

    for (int t = 0; t < ntile; t++) {
        int cur = t & 1;

        // (1) tile-t metadata + EARLY V-gathers
        int msrc[NPASS]; int msl[NPASS];
#pragma unroll
        for (int ps = 0; ps < NPASS; ps++) {
            int r = ps * RPP + rid;
            msrc[ps] = srcA[cur][r];
            msl[ps] = slotB[cur][r];
        }
        uint4 vreg[NPASS];
#pragma unroll
        for (int ps = 0; ps < NPASS; ps++)
            vreg[ps] = *(const uint4*)&Vb[(size_t)msrc[ps] * H + kk];
        char4 sscA = *(const char4*)&slotB[cur][rbase + 0];
        char4 sscB = *(const char4*)&slotB[cur][rbase + 8];
        char4 sscC = *(const char4*)&slotB[cur][rbase + 16];
        char4 sscD = *(const char4*)&slotB[cur][rbase + 24];

        // (2) prefetch CSR metadata for tile t+1
        int nsrc = 0; signed char nsl = -1;
        bool hn = (t + 1 < ntile);
        if (hn && tid < TR) {
            int p = e0 + (t + 1) * TR + tid;
            if (p < e1) { nsrc = csr_src[p]; nsl = (signed char)(csr_dst[p] - n0); }
        }

        // (3) MFMA + seg-max for tile t-1
        if (t > 0) mfma_tile(prevbuf, sspA, sspB, sspC, sspD);

        // (4) build hidden tile t
#pragma unroll
        for (int ps = 0; ps < NPASS; ps++) {
            int r = ps * RPP + rid;
            uint4 w;
            if (msl[ps] >= 0) {
                const float4 ua = *(const float4*)&U[(size_t)(n0 + msl[ps]) * H + kk];
                const float4 ub = *(const float4*)&U[(size_t)(n0 + msl[ps]) * H + kk + 4];
                const uint4 vv = vreg[ps];
                w.x = pk2(fmaxf(ua.x + bflo(vv.x), 0.f), fmaxf(ua.y + bfhi(vv.x), 0.f));
                w.y = pk2(fmaxf(ua.z + bflo(vv.y), 0.f), fmaxf(ua.w + bfhi(vv.y), 0.f));
                w.z = pk2(fmaxf(ub.x + bflo(vv.z), 0.f), fmaxf(ub.y + bfhi(vv.z), 0.f));
                w.w = pk2(fmaxf(ub.z + bflo(vv.w), 0.f), fmaxf(ub.w + bfhi(vv.w), 0.f));
            } else {
                w = (uint4){0u, 0u, 0u, 0u};
            }
            *(uint4*)&hs[cur][r * HP + kk] = w;
        }

        // (5) stage next tile's CSR metadata
        if (hn && tid < TR) { srcA[cur ^ 1][tid] = nsrc; slotB[cur ^ 1][tid] = nsl; }

        // (6) one barrier per tile
        __syncthreads();
        sspA = sscA; sspB = sscB; sspC = sscC; sspD = sscD; prevbuf = cur;
    }
    if (ntile > 0) mfma_tile(prevbuf, sspA, sspB, sspC, sspD);
    __syncthreads();

    for (int idx = tid; idx < NPG * F; idx += BLOCK) {
        int sl = idx / F, cc = idx % F;
        float m = decf(accs[sl * ACCSTR + cc]);
        float o = isfinite(m) ? (m + B2[cc]) : 0.f;
        Y[(size_t)(n0 + sl) * F + cc] = o;
    }
}

// ============================ global max-pool + FC ============================
__global__ void k_pool(const float* __restrict__ X3, const int* __restrict__ batch,
                       unsigned* poolEnc) {
    int gph = blockIdx.x;
    int seg = blockIdx.y;
    int c = threadIdx.x;
    int lo = 0, hi = NNODES;
    while (lo < hi) { int mid = (lo + hi) >> 1; if (batch[mid] < gph) lo = mid + 1; else hi = mid; }
    int start = lo;
    hi = NNODES;
    while (lo < hi) { int mid = (lo + hi) >> 1; if (batch[mid] < gph + 1) lo = mid + 1; else hi = mid; }
    int end = lo;
    int chunk = (end - start + 7) >> 3;
    int s = start + seg * chunk;
    int e = min(end, s + chunk);
    float m = -INFINITY;
    for (int n = s; n < e; n++) m = fmaxf(m, X3[(size_t)n * 256 + c]);
    atomicMax(&poolEnc[gph * 256 + c], encf(m));
}

__global__ __launch_bounds__(128) void k_fc(const unsigned* __restrict__ poolEnc,
                                            const float* __restrict__ Wfc,
                                            const float* __restrict__ Bfc,
                                            float* __restrict__ out) {
    __shared__ float p[256];
    int gph = blockIdx.x, c = threadIdx.x;
    for (int k = c; k < 256; k += 128) {
        float m = decf(poolEnc[gph * 256 + k]);
        p[k] = isfinite(m) ? m : 0.f;
    }
    __syncthreads();
    float s = Bfc[c];
    for (int k = 0; k < 256; k++) s += p[k] * Wfc[k * 128 + c];
    out[gph * 128 + c] = s;
}

// ============================ launch ============================
extern "C" void kernel_launch(void* const* d_in, const int* in_sizes, int n_in,
                              void* d_out, int out_size, void* d_ws, size_t ws_size,
                              hipStream_t stream) {
    const float* x     = (const float*)d_in[0];
    const int*   ei    = (const int*)d_in[1];
    const int*   batch = (const int*)d_in[2];
    const float* w1_1 = (const float*)d_in[3];
    const float* b1_1 = (const float*)d_in[4];
    const float* w2_1 = (const float*)d_in[5];
    const float* b2_1 = (const float*)d_in[6];
    const float* w1_2 = (const float*)d_in[7];
    const float* b1_2 = (const float*)d_in[8];
    const float* w2_2 = (const float*)d_in[9];
    const float* b2_2 = (const float*)d_in[10];
    const float* w1_3 = (const float*)d_in[11];
    const float* b1_3 = (const float*)d_in[12];
    const float* w2_3 = (const float*)d_in[13];
    const float* b2_3 = (const float*)d_in[14];
    const float* wfc  = (const float*)d_in[15];
    const float* bfc  = (const float*)d_in[16];
    float* out = (float*)d_out;

    char* ws = (char*)d_ws;
    size_t off = 0;
    auto alloc = [&](size_t bytes) {
        void* p = ws + off;
        off = (off + bytes + 255) & ~(size_t)255;
        return p;
    };
    int* deg      = (int*)alloc((size_t)NNODES * 4);
    int* cursor   = (int*)alloc((size_t)NNODES * 4);
    int* rowptr   = (int*)alloc((size_t)(NNODES + 1) * 4);
    int* bsum     = (int*)alloc(256 * 4);
    int* boff     = (int*)alloc(256 * 4);
    int* csr_src  = (int*)alloc((size_t)NEDGES * 4);
    int* csr_dst  = (int*)alloc((size_t)NEDGES * 4);
    float* U      = (float*)alloc((size_t)NNODES * 256 * 4);
    unsigned short* V = (unsigned short*)alloc((size_t)NNODES * 256 * 2);
    float* x1     = (float*)alloc((size_t)NNODES * 64 * 4);
    float* x2     = (float*)alloc((size_t)NNODES * 128 * 4);
    float* x3     = (float*)alloc((size_t)NNODES * 256 * 4);
    unsigned* poolEnc = (unsigned*)alloc((size_t)NGRAPHS * 256 * 4);
    unsigned short* w2b2 = (unsigned short*)alloc((size_t)128 * 128 * 2);
    unsigned short* w2b3 = (unsigned short*)alloc((size_t)256 * 256 * 2);
    (void)ws_size; (void)in_sizes; (void)n_in; (void)out_size;

    // CSR by dst (shared across the 3 layers) + W2 fragment prep
    k_init<<<256, 256, 0, stream>>>(deg, cursor, poolEnc);
    k_count<<<NEDGES / 256, 256, 0, stream>>>(ei, deg);
    k_scan1<<<256, 256, 0, stream>>>(deg, rowptr, bsum);
    k_scan2<<<1, 256, 0, stream>>>(bsum, boff);
    k_scan3<<<256, 256, 0, stream>>>(rowptr, boff);
    k_scatter<<<NEDGES / 256, 256, 0, stream>>>(ei, rowptr, cursor, csr_src, csr_dst);
    k_w2prep<128, 128><<<(128 * 128) / 256, 256, 0, stream>>>(w2_2, w2b2);
    k_w2prep<256, 256><<<(256 * 256) / 256, 256, 0, stream>>>(w2_3, w2b3);

    // layer 1: F_in=3, H=64, F=64   (scalar k_uv; 16x16 k_agg, NPG=64 -> 1024 blocks)
    k_uv<3, 64><<<NNODES / 16, 256, 0, stream>>>(x, w1_1, b1_1, U, V);
    k_agg<64, 64, 2, 2, 64><<<NNODES / 64, 256, 0, stream>>>(U, V, w2_1, b2_1, rowptr, csr_src, csr_dst, x1);
    // layer 2: F_in=64, H=128 — MFMA k_uv; 32x32 k_agg RWAVES=2 (512 thr), NPG=64 (68.5 KB LDS)
    k_uv_mfma<64, 128><<<NNODES / 256, 512, 0, stream>>>(x1, w1_2, b1_2, U, V);
    k_agg32<128, 128, 2, 64><<<NNODES / 64, 512, 0, stream>>>(U, V, w2b2, b2_2, rowptr, csr_src, csr_dst, x2);
    // layer 3: F_in=128, H=256 — MFMA k_uv; 32x32 k_agg RWAVES=2 (1024 thr), NPG=64 (134 KB LDS)
    k_uv_mfma<128, 256><<<NNODES / 256, 1024, 0, stream>>>(x2, w1_3, b1_3, U, V);
    k_agg32<256, 256, 2, 64><<<NNODES / 64, 1024, 0, stream>>>(U, V, w2b3, b2_3, rowptr, csr_src, csr_dst, x3);

    // global max pool + FC
    k_pool<<<dim3(NGRAPHS, 8), 256, 0, stream>>>(x3, batch, poolEnc);
    k_fc<<<NGRAPHS, 128, 0, stream>>>(poolEnc, wfc, bfc, out);
}

// Round 21
// 647.447 us; speedup vs baseline: 1.2076x; 1.0526x over previous
//
#include <hip/hip_runtime.h>
#include <hip/hip_bf16.h>
#include <math.h>

#define NNODES 65536
#define NEDGES 1048576
#define NGRAPHS 64

typedef __attribute__((ext_vector_type(8))) short short8;
typedef __attribute__((ext_vector_type(4))) float f32x4;
typedef __attribute__((ext_vector_type(16))) float f32x16;

// ---- order-preserving float<->uint encoding for atomicMax-based max ----
__device__ __forceinline__ unsigned encf(float f) {
    unsigned u = __float_as_uint(f);
    return (u & 0x80000000u) ? ~u : (u | 0x80000000u);
}
__device__ __forceinline__ float decf(unsigned u) {
    unsigned v = (u & 0x80000000u) ? (u & 0x7FFFFFFFu) : ~u;
    return __uint_as_float(v);
}
#define ENC_NEG_INF 0x007FFFFFu   // encf(-inf)

// RNE float -> bf16 bits (finite values only)
__device__ __forceinline__ unsigned bfbits(float f) {
    unsigned u = __float_as_uint(f);
    return (u + 0x7FFFu + ((u >> 16) & 1u)) >> 16;
}
__device__ __forceinline__ float bfval(unsigned bits) { return __uint_as_float(bits << 16); }
// HOT path: HW packed RNE convert (1 VALU op / 2 elems). Round-8 lesson:
// __float2bfloat16 is NOT RNE on this toolchain; v_cvt_pk_bf16_f32 is RNE
// in HW and matches bfbits (verified passing rounds 10-20).
__device__ __forceinline__ unsigned pk2(float a, float b) {
    unsigned r;
    asm("v_cvt_pk_bf16_f32 %0, %1, %2" : "=v"(r) : "v"(a), "v"(b));
    return r;   // a -> low 16, b -> high 16
}
__device__ __forceinline__ float bflo(unsigned p) { return __uint_as_float(p << 16); }
__device__ __forceinline__ float bfhi(unsigned p) { return __uint_as_float(p & 0xFFFF0000u); }

// ============================ CSR build ============================
__global__ void k_init(int* deg, int* cursor, unsigned* poolEnc) {
    int i = blockIdx.x * 256 + threadIdx.x;
    if (i < NNODES) { deg[i] = 0; cursor[i] = 0; }
    if (i < NGRAPHS * 256) poolEnc[i] = ENC_NEG_INF;
}

__global__ void k_count(const int* __restrict__ ei, int* deg) {
    int e = blockIdx.x * 256 + threadIdx.x;
    atomicAdd(&deg[ei[NEDGES + e]], 1);
}

__global__ void k_scan1(const int* __restrict__ deg, int* rowptr, int* bsum) {
    __shared__ int s[256];
    int t = threadIdx.x, b = blockIdx.x;
    int v = deg[b * 256 + t];
    s[t] = v;
    __syncthreads();
    for (int off = 1; off < 256; off <<= 1) {
        int x = (t >= off) ? s[t - off] : 0;
        __syncthreads();
        if (t >= off) s[t] += x;
        __syncthreads();
    }
    rowptr[b * 256 + t] = s[t] - v;       // local exclusive
    if (t == 255) bsum[b] = s[255];
}

__global__ void k_scan2(const int* __restrict__ bsum, int* boff) {
    __shared__ int s[256];
    int t = threadIdx.x;
    int v = bsum[t];
    s[t] = v;
    __syncthreads();
    for (int off = 1; off < 256; off <<= 1) {
        int x = (t >= off) ? s[t - off] : 0;
        __syncthreads();
        if (t >= off) s[t] += x;
        __syncthreads();
    }
    boff[t] = s[t] - v;                   // exclusive block offsets
}

__global__ void k_scan3(int* rowptr, const int* __restrict__ boff) {
    int i = blockIdx.x * 256 + threadIdx.x;
    rowptr[i] += boff[blockIdx.x];
    if (i == 0) rowptr[NNODES] = NEDGES;
}

__global__ void k_scatter(const int* __restrict__ ei, const int* __restrict__ rowptr,
                          int* cursor, int* csr_src, int* csr_dst) {
    int e = blockIdx.x * 256 + threadIdx.x;
    int s = ei[e], d = ei[NEDGES + e];
    int pos = rowptr[d] + atomicAdd(&cursor[d], 1);
    csr_src[pos] = s;
    csr_dst[pos] = d;
}

// ============ W2 -> bf16 fragment-ordered prep (for k_agg32's B loads) ============
template <int H, int F>
__global__ __launch_bounds__(256) void k_w2prep(const float* __restrict__ W2,
                                                unsigned short* __restrict__ W2b) {
    constexpr int KS16 = H / 16;
    int o = blockIdx.x * 256 + threadIdx.x;       // over H*F outputs
    int j = o & 7;
    int lane = (o >> 3) & 63;
    int t = o >> 9;
    int ks = t % KS16;
    int cw = t / KS16;
    int k = ks * 16 + (lane >> 5) * 8 + j;
    int col = cw * 32 + (lane & 31);
    W2b[o] = (unsigned short)bfbits(W2[(size_t)k * F + col]);
}

// ============================ U/V precompute ============================
// Scalar VALU version — kept for layer 1 only (FIN=3: no MFMA fit).
template <int FIN, int H>
__global__ __launch_bounds__(256) void k_uv(const float* __restrict__ X,
                                            const float* __restrict__ W1,
                                            const float* __restrict__ B1,
                                            float* __restrict__ U,
                                            unsigned short* __restrict__ Vb) {
    constexpr int NPT = (16 * H) / 256;   // nodes per thread
    __shared__ float xs[16][FIN];
    int tid = threadIdx.x;
    int n0 = blockIdx.x * 16;
    for (int idx = tid; idx < 16 * FIN; idx += 256)
        xs[idx / FIN][idx % FIN] = X[(size_t)(n0 + idx / FIN) * FIN + (idx % FIN)];
    __syncthreads();
    int h = tid & (H - 1);
    int nb = (tid / H) * NPT;
    float u[NPT], v[NPT];
    float bb = B1[h];
#pragma unroll
    for (int n = 0; n < NPT; n++) { u[n] = bb; v[n] = 0.f; }
    for (int f = 0; f < FIN; f++) {
        float wt = W1[f * H + h];
        float wb = W1[(FIN + f) * H + h];
        float wd = wt - wb;
#pragma unroll
        for (int n = 0; n < NPT; n++) {
            float xv = xs[nb + n][f];
            u[n] += xv * wd;
            v[n] += xv * wb;
        }
    }
#pragma unroll
    for (int n = 0; n < NPT; n++) {
        U[(size_t)(n0 + nb + n) * H + h] = u[n];
        Vb[(size_t)(n0 + nb + n) * H + h] = (unsigned short)bfbits(v[n]);
    }
}

// ==================== U/V precompute via MFMA (layers 2,3) ====================
// Split precision (verified round 12): S = Xhi@Whi + Xhi@Wlo + Xlo@Whi.
template <int FIN, int H>
__global__ __launch_bounds__((H / 16) * 64)
void k_uv_mfma(const float* __restrict__ X,
               const float* __restrict__ W1,
               const float* __restrict__ B1,
               float* __restrict__ U,
               unsigned short* __restrict__ Vb) {
    constexpr int WAVES = H / 16;
    constexpr int BLOCK = WAVES * 64;
    constexpr int KS = FIN / 32;          // k-steps
    constexpr int NPB = 16;               // node-tiles (of 16) per block
    constexpr int FP = FIN + 8;           // padded LDS row (bf16 units)
    static_assert(FIN % 32 == 0 && (16 * FIN) % (2 * BLOCK) == 0, "shape");

    __shared__ unsigned short xhi[16 * FP];
    __shared__ unsigned short xlo[16 * FP];

    int tid = threadIdx.x;
    int ln = tid & 15;
    int qd = (tid >> 4) & 3;
    int wv = tid >> 6;
    int col = wv * 16 + ln;

    short8 bth[KS], btl[KS], bbh[KS], bbl[KS];
#pragma unroll
    for (int ks = 0; ks < KS; ks++) {
        int kb = ks * 32 + qd * 8;
        short8 th, tl, bh, bl;
#pragma unroll
        for (int j = 0; j < 8; j++) {
            float wt = W1[(size_t)(kb + j) * H + col];
            float wb = W1[(size_t)(FIN + kb + j) * H + col];
            unsigned thb = bfbits(wt), bhb = bfbits(wb);
            th[j] = (short)thb;
            bh[j] = (short)bhb;
            tl[j] = (short)bfbits(wt - bfval(thb));
            bl[j] = (short)bfbits(wb - bfval(bhb));
        }
        bth[ks] = th; btl[ks] = tl; bbh[ks] = bh; bbl[ks] = bl;
    }

    float bias = B1[col];
    int nbase0 = blockIdx.x * (NPB * 16);

    int sidx = tid * 2;
    int snode = sidx / FIN;               // 0..15
    int sf = sidx % FIN;

    float2 xr = *(const float2*)&X[(size_t)(nbase0 + snode) * FIN + sf];

    for (int t = 0; t < NPB; t++) {
        unsigned h0 = bfbits(xr.x), h1 = bfbits(xr.y);
        unsigned l0 = bfbits(xr.x - bfval(h0));
        unsigned l1 = bfbits(xr.y - bfval(h1));
        *(unsigned*)&xhi[snode * FP + sf] = h0 | (h1 << 16);
        *(unsigned*)&xlo[snode * FP + sf] = l0 | (l1 << 16);
        if (t + 1 < NPB)
            xr = *(const float2*)&X[(size_t)(nbase0 + (t + 1) * 16 + snode) * FIN + sf];
        __syncthreads();

        f32x4 at = (f32x4){0.f, 0.f, 0.f, 0.f};
        f32x4 ab = (f32x4){0.f, 0.f, 0.f, 0.f};
#pragma unroll
        for (int ks = 0; ks < KS; ks++) {
            int ko = ks * 32 + qd * 8;
            short8 ah = *(const short8*)&xhi[ln * FP + ko];
            short8 al = *(const short8*)&xlo[ln * FP + ko];
            at = __builtin_amdgcn_mfma_f32_16x16x32_bf16(ah, bth[ks], at, 0, 0, 0);
            at = __builtin_amdgcn_mfma_f32_16x16x32_bf16(ah, btl[ks], at, 0, 0, 0);
            at = __builtin_amdgcn_mfma_f32_16x16x32_bf16(al, bth[ks], at, 0, 0, 0);
            ab = __builtin_amdgcn_mfma_f32_16x16x32_bf16(ah, bbh[ks], ab, 0, 0, 0);
            ab = __builtin_amdgcn_mfma_f32_16x16x32_bf16(ah, bbl[ks], ab, 0, 0, 0);
            ab = __builtin_amdgcn_mfma_f32_16x16x32_bf16(al, bbh[ks], ab, 0, 0, 0);
        }

        int nb = nbase0 + t * 16 + qd * 4;
#pragma unroll
        for (int j = 0; j < 4; j++) {
            U[(size_t)(nb + j) * H + col] = at[j] - ab[j] + bias;   // X@(Wt-Wb)+b
            Vb[(size_t)(nb + j) * H + col] = (unsigned short)bfbits(ab[j]); // X@Wb
        }
        __syncthreads();   // tile consumed before next overwrite
    }
}

// ================= fused edge-GEMM (MFMA bf16 16x16) + segment-max =================
// Verified round-13 version — layer 1. Round-5 pipeline + pk2 asm + NPG=64.
template <int H, int F, int RWAVES, int CWAVES, int NPG>
__global__ __launch_bounds__(RWAVES * CWAVES * 64)
void k_agg(const float* __restrict__ U,
           const unsigned short* __restrict__ Vb,
           const float* __restrict__ W2,
           const float* __restrict__ B2,
           const int* __restrict__ rowptr,
           const int* __restrict__ csr_src,
           const int* __restrict__ csr_dst,
           float* __restrict__ Y) {
    constexpr int BLOCK = RWAVES * CWAVES * 64;
    constexpr int TR = 32 * RWAVES;         // edge rows per tile
    constexpr int HP = H + 8;               // padded row (bf16 units), 16B-aligned frags
    constexpr int CPW = F / CWAVES;         // cols per wave
    constexpr int NT = CPW / 16;            // n-tiles per wave
    constexpr int KS = H / 32;              // k-steps
    constexpr int ACCSTR = F + 1;           // bank-spread accumulator stride
    constexpr int LPR = H / 8;              // threads per hidden row (8 elems each)
    constexpr int RPP = BLOCK / LPR;        // rows per construction pass
    constexpr int NPASS = TR / RPP;         // construction passes per tile
    static_assert(H % 32 == 0 && NT >= 1 && RPP >= 1 && TR % RPP == 0, "shape");
    static_assert(NPG <= 120, "slot fits signed char");

    __shared__ unsigned short hs[2][TR * HP];   // double-buffered hidden tile
    __shared__ unsigned accs[NPG * ACCSTR];     // per-slot running max (encoded)
    __shared__ int srcA[2][TR];
    __shared__ __align__(4) signed char slotB[2][TR];

    int tid = threadIdx.x;
    int n0 = blockIdx.x * NPG;

    int ln = tid & 15;              // MFMA n/m lane index
    int qd = (tid >> 4) & 3;        // MFMA quad
    int wv = tid >> 6;
    int rw = wv / CWAVES;           // row group
    int cw = wv % CWAVES;           // col wave

    short8 Bf[NT][KS];
#pragma unroll
    for (int nt = 0; nt < NT; nt++) {
        int col = cw * CPW + nt * 16 + ln;
#pragma unroll
        for (int ks = 0; ks < KS; ks++) {
            int kb = ks * 32 + qd * 8;
            short8 b;
#pragma unroll
            for (int j = 0; j < 8; j++)
                b[j] = (short)bfbits(W2[(size_t)(kb + j) * F + col]);
            Bf[nt][ks] = b;
        }
    }

    for (int idx = tid; idx < NPG * ACCSTR; idx += BLOCK) accs[idx] = ENC_NEG_INF;

    int e0 = rowptr[n0], e1 = rowptr[n0 + NPG];
    int ntile = (e1 - e0 + TR - 1) / TR;

    int rid = tid / LPR;            // construction: my row within a pass
    int kk = (tid % LPR) * 8;       // construction: my 8-elem chunk

    if (tid < TR) {
        int p = e0 + tid;
        int s = 0; signed char sl = -1;
        if (p < e1) { s = csr_src[p]; sl = (signed char)(csr_dst[p] - n0); }
        srcA[0][tid] = s; slotB[0][tid] = sl;
    }
    __syncthreads();

    auto mfma_tile = [&](int buf, char4 s0, char4 s1) {
        f32x4 acc[2][NT];
#pragma unroll
        for (int mt = 0; mt < 2; mt++)
#pragma unroll
            for (int nt = 0; nt < NT; nt++)
                acc[mt][nt] = (f32x4){0.f, 0.f, 0.f, 0.f};

#pragma unroll
        for (int ks = 0; ks < KS; ks++) {
            int ko = ks * 32 + qd * 8;
            short8 a0 = *(const short8*)&hs[buf][(rw * 32 + ln) * HP + ko];
            short8 a1 = *(const short8*)&hs[buf][(rw * 32 + 16 + ln) * HP + ko];
#pragma unroll
            for (int nt = 0; nt < NT; nt++) {
                acc[0][nt] = __builtin_amdgcn_mfma_f32_16x16x32_bf16(a0, Bf[nt][ks], acc[0][nt], 0, 0, 0);
                acc[1][nt] = __builtin_amdgcn_mfma_f32_16x16x32_bf16(a1, Bf[nt][ks], acc[1][nt], 0, 0, 0);
            }
        }

#pragma unroll
        for (int mt = 0; mt < 2; mt++) {
            char4 ss = mt ? s1 : s0;
#pragma unroll
            for (int nt = 0; nt < NT; nt++) {
                int colw = cw * CPW + nt * 16 + ln;
                float c0 = acc[mt][nt][0], c1 = acc[mt][nt][1];
                float c2 = acc[mt][nt][2], c3 = acc[mt][nt][3];
                float m3 = c3;
                float m2 = (ss.z == ss.w) ? fmaxf(c2, m3) : c2;
                float m1 = (ss.y == ss.z) ? fmaxf(c1, m2) : c1;
                float m0 = (ss.x == ss.y) ? fmaxf(c0, m1) : c0;
                if (ss.x >= 0)                 atomicMax(&accs[(int)ss.x * ACCSTR + colw], encf(m0));
                if (ss.y >= 0 && ss.y != ss.x) atomicMax(&accs[(int)ss.y * ACCSTR + colw], encf(m1));
                if (ss.z >= 0 && ss.z != ss.y) atomicMax(&accs[(int)ss.z * ACCSTR + colw], encf(m2));
                if (ss.w >= 0 && ss.w != ss.z) atomicMax(&accs[(int)ss.w * ACCSTR + colw], encf(m3));
            }
        }
    };

    char4 ssp0 = make_char4(-1, -1, -1, -1), ssp1 = make_char4(-1, -1, -1, -1);
    int prevbuf = 0;

    for (int t = 0; t < ntile; t++) {
        int cur = t & 1;

        int msrc[NPASS]; int msl[NPASS];
#pragma unroll
        for (int ps = 0; ps < NPASS; ps++) {
            int r = ps * RPP + rid;
            msrc[ps] = srcA[cur][r];
            msl[ps] = slotB[cur][r];
        }
        uint4 vreg[NPASS];
#pragma unroll
        for (int ps = 0; ps < NPASS; ps++)
            vreg[ps] = *(const uint4*)&Vb[(size_t)msrc[ps] * H + kk];   // src=0 for pad rows: safe
        char4 ssc0 = *(const char4*)&slotB[cur][rw * 32 + qd * 4];
        char4 ssc1 = *(const char4*)&slotB[cur][rw * 32 + 16 + qd * 4];

        int nsrc = 0; signed char nsl = -1;
        bool hn = (t + 1 < ntile);
        if (hn && tid < TR) {
            int p = e0 + (t + 1) * TR + tid;
            if (p < e1) { nsrc = csr_src[p]; nsl = (signed char)(csr_dst[p] - n0); }
        }

        if (t > 0) mfma_tile(prevbuf, ssp0, ssp1);

#pragma unroll
        for (int ps = 0; ps < NPASS; ps++) {
            int r = ps * RPP + rid;
            uint4 w;
            if (msl[ps] >= 0) {
                const float4 ua = *(const float4*)&U[(size_t)(n0 + msl[ps]) * H + kk];
                const float4 ub = *(const float4*)&U[(size_t)(n0 + msl[ps]) * H + kk + 4];
                const uint4 vv = vreg[ps];
                w.x = pk2(fmaxf(ua.x + bflo(vv.x), 0.f), fmaxf(ua.y + bfhi(vv.x), 0.f));
                w.y = pk2(fmaxf(ua.z + bflo(vv.y), 0.f), fmaxf(ua.w + bfhi(vv.y), 0.f));
                w.z = pk2(fmaxf(ub.x + bflo(vv.z), 0.f), fmaxf(ub.y + bfhi(vv.z), 0.f));
                w.w = pk2(fmaxf(ub.z + bflo(vv.w), 0.f), fmaxf(ub.w + bfhi(vv.w), 0.f));
            } else {
                w = (uint4){0u, 0u, 0u, 0u};
            }
            *(uint4*)&hs[cur][r * HP + kk] = w;
        }

        if (hn && tid < TR) { srcA[cur ^ 1][tid] = nsrc; slotB[cur ^ 1][tid] = nsl; }

        __syncthreads();
        ssp0 = ssc0; ssp1 = ssc1; prevbuf = cur;
    }
    if (ntile > 0) mfma_tile(prevbuf, ssp0, ssp1);
    __syncthreads();

    for (int idx = tid; idx < NPG * F; idx += BLOCK) {
        int sl = idx / F, cc = idx % F;
        float m = decf(accs[sl * ACCSTR + cc]);
        float o = isfinite(m) ? (m + B2[cc]) : 0.f;   // empty segment -> 0
        Y[(size_t)(n0 + sl) * F + cc] = o;
    }
}

// ============ fused edge-GEMM (MFMA bf16 32x32) + segment-max — layers 2,3 ============
// 32x32x16 MFMA (conflicts=0, A-redundancy F/32), B streamed from L2
// (fragment-ordered W2b, zero B-registers). RWAVES=2 / TR=64, NPG=64.
// Round-21: L3 fuses the GLOBAL MAX-POOL into the epilogue (poolEnc!=nullptr):
// x3 (64MB) was written by this kernel and read ONLY by k_pool (~128MB HBM
// round-trip + a kernel). batch[] is sorted, so a block's 64 nodes span 1-2
// graphs: each thread owns one column for 16 slots, keeps a running max per
// graph-run, flushes ONE global atomicMax per run (~1.3M atomics total).
template <int H, int F, int RWAVES, int NPG>
__global__ __launch_bounds__(RWAVES * (F / 32) * 64)
void k_agg32(const float* __restrict__ U,
             const unsigned short* __restrict__ Vb,
             const unsigned short* __restrict__ W2b,
             const float* __restrict__ B2,
             const int* __restrict__ rowptr,
             const int* __restrict__ csr_src,
             const int* __restrict__ csr_dst,
             float* __restrict__ Y,
             const int* __restrict__ batch,
             unsigned* __restrict__ poolEnc) {
    constexpr int CWAVES = F / 32;
    constexpr int BLOCK = RWAVES * CWAVES * 64;
    constexpr int TR = 32 * RWAVES;         // edge rows per tile
    constexpr int HP = H + 8;               // padded row (bf16), 16B-aligned
    constexpr int KS16 = H / 16;            // k-steps of 16
    constexpr int ACCSTR = F + 1;
    constexpr int LPR = H / 8;
    constexpr int RPP = BLOCK / LPR;
    constexpr int NPASS = TR / RPP;
    static_assert(H % 16 == 0 && TR % RPP == 0 && NPG <= 120, "shape");

    __shared__ unsigned short hs[2][TR * HP];
    __shared__ unsigned accs[NPG * ACCSTR];
    __shared__ int srcA[2][TR];
    __shared__ __align__(4) signed char slotB[2][TR];

    int tid = threadIdx.x;
    int n0 = blockIdx.x * NPG;

    int ln32 = tid & 31;            // MFMA row/col lane
    int kh = (tid >> 5) & 1;        // k-octet selector
    int wv = tid >> 6;
    int rw = wv / CWAVES;           // row group
    int cw = wv % CWAVES;           // col wave

    // per-lane base into fragment-ordered W2b: frag(cw,ks) at ((cw*KS16+ks)*64+lane)*8
    const unsigned short* Bp = W2b + ((size_t)(cw * KS16) * 64 + (tid & 63)) * 8;

    for (int idx = tid; idx < NPG * ACCSTR; idx += BLOCK) accs[idx] = ENC_NEG_INF;

    int e0 = rowptr[n0], e1 = rowptr[n0 + NPG];
    int ntile = (e1 - e0 + TR - 1) / TR;

    int rid = tid / LPR;
    int kk = (tid % LPR) * 8;

    if (tid < TR) {
        int p = e0 + tid;
        int s = 0; signed char sl = -1;
        if (p < e1) { s = csr_src[p]; sl = (signed char)(csr_dst[p] - n0); }
        srcA[0][tid] = s; slotB[0][tid] = sl;
    }
    __syncthreads();

    // MFMA + segmented max for one completed tile (B-frags streamed from L2)
    auto mfma_tile = [&](int buf, char4 sA, char4 sB, char4 sC, char4 sD) {
        f32x16 acc;
#pragma unroll
        for (int j = 0; j < 16; j++) acc[j] = 0.f;

#pragma unroll
        for (int ks = 0; ks < KS16; ks++) {
            short8 a = *(const short8*)&hs[buf][(rw * 32 + ln32) * HP + ks * 16 + kh * 8];
            short8 b = *(const short8*)&Bp[(size_t)ks * 64 * 8];
            acc = __builtin_amdgcn_mfma_f32_32x32x16_bf16(a, b, acc, 0, 0, 0);
        }

        int colw = cw * 32 + ln32;
#pragma unroll
        for (int rg = 0; rg < 4; rg++) {
            char4 ss = (rg == 0) ? sA : (rg == 1) ? sB : (rg == 2) ? sC : sD;
            float c0 = acc[4 * rg + 0], c1 = acc[4 * rg + 1];
            float c2 = acc[4 * rg + 2], c3 = acc[4 * rg + 3];
            float m3 = c3;
            float m2 = (ss.z == ss.w) ? fmaxf(c2, m3) : c2;
            float m1 = (ss.y == ss.z) ? fmaxf(c1, m2) : c1;
            float m0 = (ss.x == ss.y) ? fmaxf(c0, m1) : c0;
            if (ss.x >= 0)                 atomicMax(&accs[(int)ss.x * ACCSTR + colw], encf(m0));
            if (ss.y >= 0 && ss.y != ss.x) atomicMax(&accs[(int)ss.y * ACCSTR + colw], encf(m1));
            if (ss.z >= 0 && ss.z != ss.y) atomicMax(&accs[(int)ss.z * ACCSTR + colw], encf(m2));
            if (ss.w >= 0 && ss.w != ss.z) atomicMax(&accs[(int)ss.w * ACCSTR + colw], encf(m3));
        }
    };

    char4 sspA = make_char4(-1, -1, -1, -1), sspB = sspA, sspC = sspA, sspD = sspA;
    int prevbuf = 0;
    int rbase = rw * 32 + 4 * kh;   // my C-rows: rbase + 8*rg + {0..3}

    for (int t = 0; t < ntile; t++) {
        int cur = t & 1;

        // (1) tile-t metadata + EARLY V-gathers
        int msrc[NPASS]; int msl[NPASS];
#pragma unroll
        for (int ps = 0; ps < NPASS; ps++) {
            int r = ps * RPP + rid;
            msrc[ps] = srcA[cur][r];
            msl[ps] = slotB[cur][r];
        }
        uint4 vreg[NPASS];
#pragma unroll
        for (int ps = 0; ps < NPASS; ps++)
            vreg[ps] = *(const uint4*)&Vb[(size_t)msrc[ps] * H + kk];
        char4 sscA = *(const char4*)&slotB[cur][rbase + 0];
        char4 sscB = *(const char4*)&slotB[cur][rbase + 8];
        char4 sscC = *(const char4*)&slotB[cur][rbase + 16];
        char4 sscD = *(const char4*)&slotB[cur][rbase + 24];

        // (2) prefetch CSR metadata for tile t+1
        int nsrc = 0; signed char nsl = -1;
        bool hn = (t + 1 < ntile);
        if (hn && tid < TR) {
            int p = e0 + (t + 1) * TR + tid;
            if (p < e1) { nsrc = csr_src[p]; nsl = (signed char)(csr_dst[p] - n0); }
        }

        // (3) MFMA + seg-max for tile t-1
        if (t > 0) mfma_tile(prevbuf, sspA, sspB, sspC, sspD);

        // (4) build hidden tile t
#pragma unroll
        for (int ps = 0; ps < NPASS; ps++) {
            int r = ps * RPP + rid;
            uint4 w;
            if (msl[ps] >= 0) {
                const float4 ua = *(const float4*)&U[(size_t)(n0 + msl[ps]) * H + kk];
                const float4 ub = *(const float4*)&U[(size_t)(n0 + msl[ps]) * H + kk + 4];
                const uint4 vv = vreg[ps];
                w.x = pk2(fmaxf(ua.x + bflo(vv.x), 0.f), fmaxf(ua.y + bfhi(vv.x), 0.f));
                w.y = pk2(fmaxf(ua.z + bflo(vv.y), 0.f), fmaxf(ua.w + bfhi(vv.y), 0.f));
                w.z = pk2(fmaxf(ub.x + bflo(vv.z), 0.f), fmaxf(ub.y + bfhi(vv.z), 0.f));
                w.w = pk2(fmaxf(ub.z + bflo(vv.w), 0.f), fmaxf(ub.w + bfhi(vv.w), 0.f));
            } else {
                w = (uint4){0u, 0u, 0u, 0u};
            }
            *(uint4*)&hs[cur][r * HP + kk] = w;
        }

        // (5) stage next tile's CSR metadata
        if (hn && tid < TR) { srcA[cur ^ 1][tid] = nsrc; slotB[cur ^ 1][tid] = nsl; }

        // (6) one barrier per tile
        __syncthreads();
        sspA = sscA; sspB = sscB; sspC = sscC; sspD = sscD; prevbuf = cur;
    }
    if (ntile > 0) mfma_tile(prevbuf, sspA, sspB, sspC, sspD);
    __syncthreads();

    if (poolEnc == nullptr) {
        // normal per-node output (layer 2)
        for (int idx = tid; idx < NPG * F; idx += BLOCK) {
            int sl = idx / F, cc = idx % F;
            float m = decf(accs[sl * ACCSTR + cc]);
            float o = isfinite(m) ? (m + B2[cc]) : 0.f;   // empty segment -> 0
            Y[(size_t)(n0 + sl) * F + cc] = o;
        }
    } else {
        // fused global max-pool (layer 3): x3 never materialized.
        // BLOCK/F thread-groups; each thread owns column c for SPG slots,
        // flushes one global atomicMax per graph-run (batch sorted).
        constexpr int GRPS = BLOCK / F;       // 1024/256 = 4
        constexpr int SPG = NPG / GRPS;       // 64/4 = 16
        int c = tid & (F - 1);
        int grp = tid / F;                    // 0..GRPS-1
        int sbase = grp * SPG;
        float bb = B2[c];
        int curg = batch[n0 + sbase];
        float run = -INFINITY;
#pragma unroll
        for (int s = 0; s < SPG; s++) {
            int sl = sbase + s;
            float m = decf(accs[sl * ACCSTR + c]);
            float o = isfinite(m) ? (m + bb) : 0.f;
            int g = batch[n0 + sl];
            if (g != curg) {
                atomicMax(&poolEnc[(size_t)curg * F + c], encf(run));
                curg = g; run = -INFINITY;
            }
            run = fmaxf(run, o);
        }
        atomicMax(&poolEnc[(size_t)curg * F + c], encf(run));
    }
}

// ============================ FC ============================
__global__ __launch_bounds__(128) void k_fc(const unsigned* __restrict__ poolEnc,
                                            const float* __restrict__ Wfc,
                                            const float* __restrict__ Bfc,
                                            float* __restrict__ out) {
    __shared__ float p[256];
    int gph = blockIdx.x, c = threadIdx.x;
    for (int k = c; k < 256; k += 128) {
        float m = decf(poolEnc[gph * 256 + k]);
        p[k] = isfinite(m) ? m : 0.f;
    }
    __syncthreads();
    float s = Bfc[c];
    for (int k = 0; k < 256; k++) s += p[k] * Wfc[k * 128 + c];
    out[gph * 128 + c] = s;
}

// ============================ launch ============================
extern "C" void kernel_launch(void* const* d_in, const int* in_sizes, int n_in,
                              void* d_out, int out_size, void* d_ws, size_t ws_size,
                              hipStream_t stream) {
    const float* x     = (const float*)d_in[0];
    const int*   ei    = (const int*)d_in[1];
    const int*   batch = (const int*)d_in[2];
    const float* w1_1 = (const float*)d_in[3];
    const float* b1_1 = (const float*)d_in[4];
    const float* w2_1 = (const float*)d_in[5];
    const float* b2_1 = (const float*)d_in[6];
    const float* w1_2 = (const float*)d_in[7];
    const float* b1_2 = (const float*)d_in[8];
    const float* w2_2 = (const float*)d_in[9];
    const float* b2_2 = (const float*)d_in[10];
    const float* w1_3 = (const float*)d_in[11];
    const float* b1_3 = (const float*)d_in[12];
    const float* w2_3 = (const float*)d_in[13];
    const float* b2_3 = (const float*)d_in[14];
    const float* wfc  = (const float*)d_in[15];
    const float* bfc  = (const float*)d_in[16];
    float* out = (float*)d_out;

    char* ws = (char*)d_ws;
    size_t off = 0;
    auto alloc = [&](size_t bytes) {
        void* p = ws + off;
        off = (off + bytes + 255) & ~(size_t)255;
        return p;
    };
    int* deg      = (int*)alloc((size_t)NNODES * 4);
    int* cursor   = (int*)alloc((size_t)NNODES * 4);
    int* rowptr   = (int*)alloc((size_t)(NNODES + 1) * 4);
    int* bsum     = (int*)alloc(256 * 4);
    int* boff     = (int*)alloc(256 * 4);
    int* csr_src  = (int*)alloc((size_t)NEDGES * 4);
    int* csr_dst  = (int*)alloc((size_t)NEDGES * 4);
    float* U      = (float*)alloc((size_t)NNODES * 256 * 4);
    unsigned short* V = (unsigned short*)alloc((size_t)NNODES * 256 * 2);
    float* x1     = (float*)alloc((size_t)NNODES * 64 * 4);
    float* x2     = (float*)alloc((size_t)NNODES * 128 * 4);
    unsigned* poolEnc = (unsigned*)alloc((size_t)NGRAPHS * 256 * 4);
    unsigned short* w2b2 = (unsigned short*)alloc((size_t)128 * 128 * 2);
    unsigned short* w2b3 = (unsigned short*)alloc((size_t)256 * 256 * 2);
    (void)ws_size; (void)in_sizes; (void)n_in; (void)out_size;

    // CSR by dst (shared across the 3 layers) + W2 fragment prep
    k_init<<<256, 256, 0, stream>>>(deg, cursor, poolEnc);
    k_count<<<NEDGES / 256, 256, 0, stream>>>(ei, deg);
    k_scan1<<<256, 256, 0, stream>>>(deg, rowptr, bsum);
    k_scan2<<<1, 256, 0, stream>>>(bsum, boff);
    k_scan3<<<256, 256, 0, stream>>>(rowptr, boff);
    k_scatter<<<NEDGES / 256, 256, 0, stream>>>(ei, rowptr, cursor, csr_src, csr_dst);
    k_w2prep<128, 128><<<(128 * 128) / 256, 256, 0, stream>>>(w2_2, w2b2);
    k_w2prep<256, 256><<<(256 * 256) / 256, 256, 0, stream>>>(w2_3, w2b3);

    // layer 1: F_in=3, H=64, F=64   (scalar k_uv; 16x16 k_agg, NPG=64)
    k_uv<3, 64><<<NNODES / 16, 256, 0, stream>>>(x, w1_1, b1_1, U, V);
    k_agg<64, 64, 2, 2, 64><<<NNODES / 64, 256, 0, stream>>>(U, V, w2_1, b2_1, rowptr, csr_src, csr_dst, x1);
    // layer 2: F_in=64, H=128 — MFMA k_uv; 32x32 k_agg RWAVES=2 (512 thr), NPG=64
    k_uv_mfma<64, 128><<<NNODES / 256, 512, 0, stream>>>(x1, w1_2, b1_2, U, V);
    k_agg32<128, 128, 2, 64><<<NNODES / 64, 512, 0, stream>>>(U, V, w2b2, b2_2, rowptr, csr_src, csr_dst, x2, nullptr, nullptr);
    // layer 3: F_in=128, H=256 — MFMA k_uv; 32x32 k_agg RWAVES=2 (1024 thr), NPG=64,
    // FUSED POOL epilogue (x3 never materialized; k_pool removed)
    k_uv_mfma<128, 256><<<NNODES / 256, 1024, 0, stream>>>(x2, w1_3, b1_3, U, V);
    k_agg32<256, 256, 2, 64><<<NNODES / 64, 1024, 0, stream>>>(U, V, w2b3, b2_3, rowptr, csr_src, csr_dst, nullptr, batch, poolEnc);

    // FC
    k_fc<<<NGRAPHS, 128, 0, stream>>>(poolEnc, wfc, bfc, out);
}